// Round 3
// baseline (889.667 us; speedup 1.0000x reference)
//
#include <hip/hip_runtime.h>

// MACE layer, fp32 I/O. N=20000 nodes, E=320000 edges, F=64, P=5, R=8, H=64, S=10.
// d_out (fp32, 20.56 MB) doubles as the fp32 A_s/A_v atomic accumulator:
//   A_s [N,64]  aliases s_out slot (identical per-node layout)
//   A_v [N,3,64] aliases v_out slot (same 192-float per-node slot, transposed inside)
// Kernel C reads slot n then overwrites slot n -> no cross-node hazard.
// Workspace: only 10.24 MB of bf16-packed s1/v1 temporaries.
#define NNODES 20000
#define NEDGES 320000

__device__ __forceinline__ float bitsf(unsigned u){ union{unsigned u; float f;} x; x.u=u; return x.f; }
__device__ __forceinline__ float b2f(unsigned short u){ return bitsf(((unsigned)u)<<16); }
__device__ __forceinline__ unsigned short f2b(float f){
    union{float f; unsigned u;} x; x.f=f;
    unsigned r = x.u + 0x7fffu + ((x.u>>16)&1u);   // RNE
    return (unsigned short)(r>>16);
}

__constant__ float kINV_SQRT3 = 0.5773502691896258f;
__constant__ float kINV_SQRT2 = 0.7071067811865476f;
__constant__ float kINV_AVG   = 0.25f;             // 1/sqrt(16)

// ---------------- Kernel A: s1 = s@W_lin_s ; v1 = v@W_lin_v (bf16 into ws) ---------------
__global__ __launch_bounds__(256) void knodeA(
    const float* __restrict__ s, const float* __restrict__ v,
    const float* __restrict__ Wls, const float* __restrict__ Wlv,
    unsigned short* __restrict__ s1, unsigned short* __restrict__ v1)
{
    __shared__ float lWls[4096], lWlv[4096];
    for (int i = threadIdx.x; i < 4096; i += 256){ lWls[i] = Wls[i]; lWlv[i] = Wlv[i]; }
    __syncthreads();
    const int lane = threadIdx.x & 63;
    const int wave = threadIdx.x >> 6;
    for (int it = 0; it < 4; ++it){
        const int n = blockIdx.x * 16 + it * 4 + wave;
        float sv  = s[n*64 + lane];
        float v0  = v[(n*64 + lane)*3 + 0];
        float v1r = v[(n*64 + lane)*3 + 1];
        float v2r = v[(n*64 + lane)*3 + 2];
        float a_s=0.f, a0=0.f, a1=0.f, a2=0.f;
        #pragma unroll 16
        for (int f = 0; f < 64; ++f){
            float sf  = __shfl(sv, f);
            float vf0 = __shfl(v0, f), vf1 = __shfl(v1r, f), vf2 = __shfl(v2r, f);
            float wls = lWls[f*64 + lane], wlv = lWlv[f*64 + lane];
            a_s += sf*wls; a0 += vf0*wlv; a1 += vf1*wlv; a2 += vf2*wlv;
        }
        s1[n*64+lane] = f2b(a_s);
        v1[(n*3+0)*64+lane] = f2b(a0);
        v1[(n*3+1)*64+lane] = f2b(a1);
        v1[(n*3+2)*64+lane] = f2b(a2);
    }
}

// ---------------- Kernel B: per-edge radial MLP + CG tensor product + atomic scatter ------
__global__ __launch_bounds__(256) void kedge(
    const float* __restrict__ Y1, const float* __restrict__ ef,
    const int* __restrict__ senders, const int* __restrict__ receivers,
    const float* __restrict__ Wr1, const float* __restrict__ Wr2,
    const unsigned short* __restrict__ s1, const unsigned short* __restrict__ v1,
    float* __restrict__ As, float* __restrict__ Av)
{
    __shared__ float lWr1[512];          // [r][j] fp32
    __shared__ uint2    lW2a[4096];      // [j][f]: (p0|p1<<16, p2|p3<<16) bf16-packed
    __shared__ unsigned lW2b[4096];      // [j][f]: p4
    for (int i = threadIdx.x; i < 512; i += 256) lWr1[i] = Wr1[i];
    for (int idx = threadIdx.x; idx < 4096; idx += 256){
        int j = idx >> 6, f = idx & 63;
        unsigned p0 = f2b(Wr2[j*320 +   0 + f]);
        unsigned p1 = f2b(Wr2[j*320 +  64 + f]);
        unsigned p2 = f2b(Wr2[j*320 + 128 + f]);
        unsigned p3 = f2b(Wr2[j*320 + 192 + f]);
        unsigned p4 = f2b(Wr2[j*320 + 256 + f]);
        lW2a[idx] = make_uint2(p0 | (p1<<16), p2 | (p3<<16));
        lW2b[idx] = p4;
    }
    __syncthreads();
    const int lane = threadIdx.x & 63;
    const int wave = threadIdx.x >> 6;
    for (int it = 0; it < 8; ++it){
        const int e = blockIdx.x * 32 + it*4 + wave;
        // radial MLP layer 1: h[j], lane = j
        float efv = (lane < 8) ? ef[e*8 + lane] : 0.f;
        float h = 0.f;
        #pragma unroll
        for (int r = 0; r < 8; ++r) h += __shfl(efv, r) * lWr1[r*64 + lane];
        h = h / (1.f + __expf(-h));                     // silu
        // radial MLP layer 2: tw[p] for lane's channel f
        float tw0=0,tw1=0,tw2=0,tw3=0,tw4=0;
        #pragma unroll 8
        for (int j = 0; j < 64; ++j){
            float hj = __shfl(h, j);
            uint2 wa = lW2a[j*64 + lane];
            unsigned wb = lW2b[j*64 + lane];
            tw0 += hj * bitsf(wa.x << 16);
            tw1 += hj * bitsf(wa.x & 0xffff0000u);
            tw2 += hj * bitsf(wa.y << 16);
            tw3 += hj * bitsf(wa.y & 0xffff0000u);
            tw4 += hj * bitsf(wb << 16);
        }
        // gather sender features, CG tensor product
        const int snd = senders[e], rcv = receivers[e];
        float ss  = b2f(s1[snd*64 + lane]);
        float vs0 = b2f(v1[(snd*3+0)*64 + lane]);
        float vs1 = b2f(v1[(snd*3+1)*64 + lane]);
        float vs2 = b2f(v1[(snd*3+2)*64 + lane]);
        float y0 = Y1[e*3+0], y1 = Y1[e*3+1], y2 = Y1[e*3+2];
        float dot = vs0*y0 + vs1*y1 + vs2*y2;
        float c0 = vs1*y2 - vs2*y1;
        float c1 = vs2*y0 - vs0*y2;
        float c2 = vs0*y1 - vs1*y0;
        float ms  = tw0*ss + tw1*dot*kINV_SQRT3;
        float t2s = tw2*ss, t4 = tw4*kINV_SQRT2;
        float mv0 = t2s*y0 + tw3*vs0 + t4*c0;
        float mv1 = t2s*y1 + tw3*vs1 + t4*c1;
        float mv2 = t2s*y2 + tw3*vs2 + t4*c2;
        unsafeAtomicAdd(&As[rcv*64 + lane], ms);
        unsafeAtomicAdd(&Av[(rcv*3+0)*64 + lane], mv0);
        unsafeAtomicAdd(&Av[(rcv*3+1)*64 + lane], mv1);
        unsafeAtomicAdd(&Av[(rcv*3+2)*64 + lane], mv2);
    }
}

// ---- Kernel C: W_int, product basis, W_prod, species skip (recomputed), readout ----------
// `out` is NOT __restrict__: A_s/A_v are read from the same slots that s_out/v_out
// overwrite (per-node aliasing is intentional).
__global__ __launch_bounds__(256) void knodeC(
    const int* __restrict__ specie,
    const float* __restrict__ s, const float* __restrict__ v,
    const float* __restrict__ Wis, const float* __restrict__ Wiv,
    const float* __restrict__ Wss, const float* __restrict__ Wsv,
    const float* __restrict__ wps, const float* __restrict__ wpv,
    const float* __restrict__ Wps, const float* __restrict__ Wpv,
    const float* __restrict__ Wread,
    float* out)
{
    __shared__ float lWis[4096], lWiv[4096];      // fp32, 32 KB
    __shared__ unsigned short lWps[4096], lWpv[4096];  // bf16, 16 KB
    for (int i = threadIdx.x; i < 4096; i += 256){
        lWis[i] = Wis[i]; lWiv[i] = Wiv[i];
        lWps[i] = f2b(Wps[i]); lWpv[i] = f2b(Wpv[i]);
    }
    __syncthreads();
    const int lane = threadIdx.x & 63;
    const int wave = threadIdx.x >> 6;
    float* out_node = out;                  // [N]
    float* out_s    = out + NNODES;         // [N,64]   (aliases A_s)
    float* out_v    = out + NNODES + NNODES*64;  // [N,64,3] (aliases A_v [N,3,64])
    const float* As = out + NNODES;
    const float* Av = out + NNODES + NNODES*64;
    for (int it = 0; it < 4; ++it){
        const int n = blockIdx.x*16 + it*4 + wave;
        float as  = As[n*64 + lane];
        float av0 = Av[(n*3+0)*64+lane], av1 = Av[(n*3+1)*64+lane], av2 = Av[(n*3+2)*64+lane];
        // original inputs for the species skip
        float sv  = s[n*64 + lane];
        float vv0 = v[(n*64 + lane)*3 + 0];
        float vv1 = v[(n*64 + lane)*3 + 1];
        float vv2 = v[(n*64 + lane)*3 + 2];
        const int spec = specie[n];
        const float* pss = Wss + spec*4096;
        const float* psv = Wsv + spec*4096;
        float Ais=0.f, Aiv0=0.f, Aiv1=0.f, Aiv2=0.f;
        float scs=0.f, scv0=0.f, scv1=0.f, scv2=0.f;
        #pragma unroll 8
        for (int f=0; f<64; ++f){
            float af  = __shfl(as, f);
            float a0f = __shfl(av0,f), a1f = __shfl(av1,f), a2f = __shfl(av2,f);
            float sf  = __shfl(sv, f);
            float w0f = __shfl(vv0,f), w1f = __shfl(vv1,f), w2f = __shfl(vv2,f);
            float wis = lWis[f*64+lane], wiv = lWiv[f*64+lane];
            float wss = pss[f*64+lane], wsv = psv[f*64+lane];
            Ais += af*wis; Aiv0 += a0f*wiv; Aiv1 += a1f*wiv; Aiv2 += a2f*wiv;
            scs += sf*wss; scv0 += w0f*wsv; scv1 += w1f*wsv; scv2 += w2f*wsv;
        }
        Ais *= kINV_AVG; Aiv0 *= kINV_AVG; Aiv1 *= kINV_AVG; Aiv2 *= kINV_AVG;
        float d = Aiv0*Aiv0 + Aiv1*Aiv1 + Aiv2*Aiv2;
        const float* pw = wps + spec*5*64;
        const float* pu = wpv + spec*4*64;
        float w0 = pw[0*64+lane], w1 = pw[1*64+lane], w2 = pw[2*64+lane];
        float w3 = pw[3*64+lane], w4 = pw[4*64+lane];
        float u0 = pu[0*64+lane], u1 = pu[1*64+lane];
        float u2 = pu[2*64+lane], u3 = pu[3*64+lane];
        float as2 = Ais*Ais;
        float Bs = w0*Ais + w1*as2 + w2*d + w3*as2*Ais + w4*Ais*d;
        float g  = u0 + u1*Ais + u2*as2 + u3*d;
        float Bv0 = g*Aiv0, Bv1 = g*Aiv1, Bv2 = g*Aiv2;
        float so=0.f, vo0=0.f, vo1=0.f, vo2=0.f;
        #pragma unroll 16
        for (int f=0; f<64; ++f){
            float bsf = __shfl(Bs, f);
            float bv0f = __shfl(Bv0,f), bv1f = __shfl(Bv1,f), bv2f = __shfl(Bv2,f);
            float wp = b2f(lWps[f*64+lane]), wv = b2f(lWpv[f*64+lane]);
            so += bsf*wp; vo0 += bv0f*wv; vo1 += bv1f*wv; vo2 += bv2f*wv;
        }
        so  += scs;
        vo0 += scv0; vo1 += scv1; vo2 += scv2;
        // overwrite THIS node's slots (reads of node n completed above)
        out_s[n*64+lane] = so;
        out_v[(n*64+lane)*3+0] = vo0;
        out_v[(n*64+lane)*3+1] = vo1;
        out_v[(n*64+lane)*3+2] = vo2;
        float r = so * Wread[lane];
        #pragma unroll
        for (int off=32; off>0; off>>=1) r += __shfl_xor(r, off);
        if (lane == 0) out_node[n] = r;
    }
}

extern "C" void kernel_launch(void* const* d_in, const int* in_sizes, int n_in,
                              void* d_out, int out_size, void* d_ws, size_t ws_size,
                              hipStream_t stream)
{
    (void)in_sizes; (void)n_in; (void)out_size; (void)ws_size;
    const float* s    = (const float*)d_in[0];
    const float* v    = (const float*)d_in[1];
    const float* Y1   = (const float*)d_in[2];
    const float* ef   = (const float*)d_in[3];
    const int* specie = (const int*)d_in[4];
    const int* senders   = (const int*)d_in[5];
    const int* receivers = (const int*)d_in[6];
    const float* Wls  = (const float*)d_in[7];
    const float* Wlv  = (const float*)d_in[8];
    const float* Wss  = (const float*)d_in[9];
    const float* Wsv  = (const float*)d_in[10];
    const float* Wr1  = (const float*)d_in[11];
    const float* Wr2  = (const float*)d_in[12];
    const float* Wis  = (const float*)d_in[13];
    const float* Wiv  = (const float*)d_in[14];
    const float* wps  = (const float*)d_in[15];
    const float* wpv  = (const float*)d_in[16];
    const float* Wps  = (const float*)d_in[17];
    const float* Wpv  = (const float*)d_in[18];
    const float* Wrd  = (const float*)d_in[19];

    float* out = (float*)d_out;
    float* As  = out + NNODES;              // [N,64]  fp32 accumulator (aliases s_out)
    float* Av  = out + NNODES + NNODES*64;  // [N,3,64] fp32 accumulator (aliases v_out)

    // workspace: bf16 s1 [N,64] + v1 [N,3,64]  (10.24 MB total)
    unsigned short* t_s1 = (unsigned short*)d_ws;
    unsigned short* t_v1 = t_s1 + NNODES*64;

    // zero the accumulator region (s_out+v_out slots of d_out): 20,480,000 bytes
    hipMemsetAsync(As, 0, (size_t)NNODES*(64+192)*4, stream);
    knodeA<<<1250, 256, 0, stream>>>(s, v, Wls, Wlv, t_s1, t_v1);
    kedge<<<10000, 256, 0, stream>>>(Y1, ef, senders, receivers, Wr1, Wr2, t_s1, t_v1, As, Av);
    knodeC<<<1250, 256, 0, stream>>>(specie, s, v, Wis, Wiv, Wss, Wsv,
                                     wps, wpv, Wps, Wpv, Wrd, out);
}

// Round 4
// 637.803 us; speedup vs baseline: 1.3949x; 1.3949x over previous
//
#include <hip/hip_runtime.h>

// MACE layer, fp32 I/O. N=20000, E=320000, F=64, P=5, R=8, H=64, S=10.
// R4: kedge's radial-MLP layer 2 (tw = h @ W_rad2, 13.1 GF) moved to MFMA
// (v_mfma_f32_16x16x32_bf16). W_rad2 pre-swizzled once into B-fragment order
// (40 KB bf16, L2-hot, loaded per-wave as coalesced dwordx4). TP + atomic
// scatter unchanged. d_out still doubles as fp32 A accumulator (per-node
// slot aliasing, kernel C reads-then-overwrites its own slot).
#define NNODES 20000
#define NEDGES 320000

typedef __attribute__((ext_vector_type(8))) short short8;    // 8 bf16 (4 VGPRs)
typedef __attribute__((ext_vector_type(4))) float float4v;   // MFMA acc

__device__ __forceinline__ float bitsf(unsigned u){ union{unsigned u; float f;} x; x.u=u; return x.f; }
__device__ __forceinline__ float b2f(unsigned short u){ return bitsf(((unsigned)u)<<16); }
__device__ __forceinline__ unsigned short f2b(float f){
    union{float f; unsigned u;} x; x.f=f;
    unsigned r = x.u + 0x7fffu + ((x.u>>16)&1u);   // RNE
    return (unsigned short)(r>>16);
}

__constant__ float kINV_SQRT3 = 0.5773502691896258f;
__constant__ float kINV_SQRT2 = 0.7071067811865476f;
__constant__ float kINV_AVG   = 0.25f;             // 1/sqrt(16)

// ---- Pre-kernel: swizzle W_rad2 [64][320] fp32 -> bf16 B-fragments ----------------------
// Layout: chunk c = (nt*2+ks)*64+lane holds B[k=ks*32+(lane>>4)*8+jj][n=nt*16+(lane&15)],
// jj=0..7 contiguous. One 16B chunk per (frag,lane). 2560 chunks = 40960 B.
__global__ void kprepW2(const float* __restrict__ Wr2, unsigned short* __restrict__ W2s)
{
    for (int c = threadIdx.x; c < 2560; c += 256){
        const int nt = c >> 7, ks = (c >> 6) & 1, ln = c & 63;
        const int col = nt*16 + (ln & 15);
        const int jb  = ks*32 + ((ln >> 4) & 3)*8;
        unsigned short t[8];
        #pragma unroll
        for (int jj = 0; jj < 8; ++jj) t[jj] = f2b(Wr2[(jb+jj)*320 + col]);
        unsigned* d = (unsigned*)(W2s + c*8);
        d[0] = (unsigned)t[0] | ((unsigned)t[1]<<16);
        d[1] = (unsigned)t[2] | ((unsigned)t[3]<<16);
        d[2] = (unsigned)t[4] | ((unsigned)t[5]<<16);
        d[3] = (unsigned)t[6] | ((unsigned)t[7]<<16);
    }
}

// ---------------- Kernel A: s1 = s@W_lin_s ; v1 = v@W_lin_v (bf16 into ws) ---------------
__global__ __launch_bounds__(256) void knodeA(
    const float* __restrict__ s, const float* __restrict__ v,
    const float* __restrict__ Wls, const float* __restrict__ Wlv,
    unsigned short* __restrict__ s1, unsigned short* __restrict__ v1)
{
    __shared__ float lWls[4096], lWlv[4096];
    for (int i = threadIdx.x; i < 4096; i += 256){ lWls[i] = Wls[i]; lWlv[i] = Wlv[i]; }
    __syncthreads();
    const int lane = threadIdx.x & 63;
    const int wave = threadIdx.x >> 6;
    for (int it = 0; it < 4; ++it){
        const int n = blockIdx.x * 16 + it * 4 + wave;
        float sv  = s[n*64 + lane];
        float v0  = v[(n*64 + lane)*3 + 0];
        float v1r = v[(n*64 + lane)*3 + 1];
        float v2r = v[(n*64 + lane)*3 + 2];
        float a_s=0.f, a0=0.f, a1=0.f, a2=0.f;
        #pragma unroll 16
        for (int f = 0; f < 64; ++f){
            float sf  = __shfl(sv, f);
            float vf0 = __shfl(v0, f), vf1 = __shfl(v1r, f), vf2 = __shfl(v2r, f);
            float wls = lWls[f*64 + lane], wlv = lWlv[f*64 + lane];
            a_s += sf*wls; a0 += vf0*wlv; a1 += vf1*wlv; a2 += vf2*wlv;
        }
        s1[n*64+lane] = f2b(a_s);
        v1[(n*3+0)*64+lane] = f2b(a0);
        v1[(n*3+1)*64+lane] = f2b(a1);
        v1[(n*3+2)*64+lane] = f2b(a2);
    }
}

// ---- Kernel B (R4): layer1 -> MFMA tw-GEMM -> TP -> atomic scatter ----------------------
// Block = 64 edges, wave = 16 edges. MFMA 16x16x32 bf16: M=16 edges, N=320, K=64.
// A-frag (h): lane l -> h[e=l&15][k=(l>>4)*8+j].  B-frag: pre-swizzled W2s.
// C/D: lane l, reg r -> D[e=(l>>4)*4+r][pf=nt*16+(l&15)]  (m89-verified mapping).
__global__ __launch_bounds__(256) void kedge2(
    const float* __restrict__ Y1, const float* __restrict__ ef,
    const int* __restrict__ senders, const int* __restrict__ receivers,
    const float* __restrict__ Wr1, const unsigned short* __restrict__ W2s,
    const unsigned short* __restrict__ s1, const unsigned short* __restrict__ v1,
    float* __restrict__ As, float* __restrict__ Av)
{
    __shared__ unsigned short hlds[64*72];    // h tile, stride 72 bf16 (144 B, 16B-aligned)
    __shared__ unsigned short twlds[64*330];  // tw tile, stride 330 bf16 (conflict-free-ish)
    const int lane = threadIdx.x & 63;
    const int w    = threadIdx.x >> 6;
    const int ew   = blockIdx.x*64 + w*16;    // this wave's first edge

    // ---- stage: per-wave edge metadata + radial layer 1 ----
    float ef0 = ef[ew*8 + lane];              // edges ew..ew+7, r=lane&7
    float ef1 = ef[ew*8 + 64 + lane];         // edges ew+8..ew+15
    float w1r[8];
    #pragma unroll
    for (int r = 0; r < 8; ++r) w1r[r] = Wr1[r*64 + lane];
    float yreg  = (lane < 48) ? Y1[ew*3 + lane] : 0.f;
    int sndreg  = (lane < 16) ? senders[ew + lane]   : 0;
    int rcvreg  = (lane < 16) ? receivers[ew + lane] : 0;
    #pragma unroll
    for (int e16 = 0; e16 < 16; ++e16){
        float src = (e16 < 8) ? ef0 : ef1;
        float hj = 0.f;
        #pragma unroll
        for (int r = 0; r < 8; ++r) hj += __shfl(src, (e16&7)*8 + r) * w1r[r];
        hj = hj / (1.f + __expf(-hj));        // silu
        hlds[(w*16 + e16)*72 + lane] = f2b(hj);
    }
    __syncthreads();

    // ---- MFMA GEMM: tw[16 e][320] = h[16,64] @ W2[64,320] ----
    short8 a0 = *(const short8*)&hlds[(w*16 + (lane&15))*72 +      (lane>>4)*8];
    short8 a1 = *(const short8*)&hlds[(w*16 + (lane&15))*72 + 32 + (lane>>4)*8];
    float4v acc[20];
    #pragma unroll
    for (int nt = 0; nt < 20; ++nt){
        short8 b0 = *(const short8*)&W2s[((nt*2+0)*64 + lane)*8];
        short8 b1 = *(const short8*)&W2s[((nt*2+1)*64 + lane)*8];
        float4v z = {0.f, 0.f, 0.f, 0.f};
        acc[nt] = __builtin_amdgcn_mfma_f32_16x16x32_bf16(a0, b0, z, 0, 0, 0);
        acc[nt] = __builtin_amdgcn_mfma_f32_16x16x32_bf16(a1, b1, acc[nt], 0, 0, 0);
    }
    // acc -> LDS (bf16). Wave reads back only its own rows -> no barrier needed.
    #pragma unroll
    for (int nt = 0; nt < 20; ++nt){
        const int col = nt*16 + (lane & 15);
        #pragma unroll
        for (int r = 0; r < 4; ++r){
            const int erow = w*16 + (lane>>4)*4 + r;
            twlds[erow*330 + col] = f2b(acc[nt][r]);
        }
    }

    // ---- TP + scatter: lane = channel f ----
    for (int e16 = 0; e16 < 16; ++e16){
        const int erow = w*16 + e16;
        float tw0 = b2f(twlds[erow*330 +   0 + lane]);
        float tw1 = b2f(twlds[erow*330 +  64 + lane]);
        float tw2 = b2f(twlds[erow*330 + 128 + lane]);
        float tw3 = b2f(twlds[erow*330 + 192 + lane]);
        float tw4 = b2f(twlds[erow*330 + 256 + lane]);
        const int snd = __shfl(sndreg, e16);
        const int rcv = __shfl(rcvreg, e16);
        float y0 = __shfl(yreg, e16*3+0);
        float y1 = __shfl(yreg, e16*3+1);
        float y2 = __shfl(yreg, e16*3+2);
        float ss  = b2f(s1[snd*64 + lane]);
        float vs0 = b2f(v1[(snd*3+0)*64 + lane]);
        float vs1 = b2f(v1[(snd*3+1)*64 + lane]);
        float vs2 = b2f(v1[(snd*3+2)*64 + lane]);
        float dot = vs0*y0 + vs1*y1 + vs2*y2;
        float c0 = vs1*y2 - vs2*y1;
        float c1 = vs2*y0 - vs0*y2;
        float c2 = vs0*y1 - vs1*y0;
        float ms  = tw0*ss + tw1*dot*kINV_SQRT3;
        float t2s = tw2*ss, t4 = tw4*kINV_SQRT2;
        float mv0 = t2s*y0 + tw3*vs0 + t4*c0;
        float mv1 = t2s*y1 + tw3*vs1 + t4*c1;
        float mv2 = t2s*y2 + tw3*vs2 + t4*c2;
        unsafeAtomicAdd(&As[rcv*64 + lane], ms);
        unsafeAtomicAdd(&Av[(rcv*3+0)*64 + lane], mv0);
        unsafeAtomicAdd(&Av[(rcv*3+1)*64 + lane], mv1);
        unsafeAtomicAdd(&Av[(rcv*3+2)*64 + lane], mv2);
    }
}

// ---- Kernel C: W_int, product basis, W_prod, species skip (recomputed), readout ----------
__global__ __launch_bounds__(256) void knodeC(
    const int* __restrict__ specie,
    const float* __restrict__ s, const float* __restrict__ v,
    const float* __restrict__ Wis, const float* __restrict__ Wiv,
    const float* __restrict__ Wss, const float* __restrict__ Wsv,
    const float* __restrict__ wps, const float* __restrict__ wpv,
    const float* __restrict__ Wps, const float* __restrict__ Wpv,
    const float* __restrict__ Wread,
    float* out)   // NOT __restrict__: reads A from slots it overwrites
{
    __shared__ float lWis[4096], lWiv[4096];
    __shared__ unsigned short lWps[4096], lWpv[4096];
    for (int i = threadIdx.x; i < 4096; i += 256){
        lWis[i] = Wis[i]; lWiv[i] = Wiv[i];
        lWps[i] = f2b(Wps[i]); lWpv[i] = f2b(Wpv[i]);
    }
    __syncthreads();
    const int lane = threadIdx.x & 63;
    const int wave = threadIdx.x >> 6;
    float* out_node = out;
    float* out_s    = out + NNODES;
    float* out_v    = out + NNODES + NNODES*64;
    const float* As = out + NNODES;
    const float* Av = out + NNODES + NNODES*64;
    for (int it = 0; it < 4; ++it){
        const int n = blockIdx.x*16 + it*4 + wave;
        float as  = As[n*64 + lane];
        float av0 = Av[(n*3+0)*64+lane], av1 = Av[(n*3+1)*64+lane], av2 = Av[(n*3+2)*64+lane];
        float sv  = s[n*64 + lane];
        float vv0 = v[(n*64 + lane)*3 + 0];
        float vv1 = v[(n*64 + lane)*3 + 1];
        float vv2 = v[(n*64 + lane)*3 + 2];
        const int spec = specie[n];
        const float* pss = Wss + spec*4096;
        const float* psv = Wsv + spec*4096;
        float Ais=0.f, Aiv0=0.f, Aiv1=0.f, Aiv2=0.f;
        float scs=0.f, scv0=0.f, scv1=0.f, scv2=0.f;
        #pragma unroll 8
        for (int f=0; f<64; ++f){
            float af  = __shfl(as, f);
            float a0f = __shfl(av0,f), a1f = __shfl(av1,f), a2f = __shfl(av2,f);
            float sf  = __shfl(sv, f);
            float w0f = __shfl(vv0,f), w1f = __shfl(vv1,f), w2f = __shfl(vv2,f);
            float wis = lWis[f*64+lane], wiv = lWiv[f*64+lane];
            float wss = pss[f*64+lane], wsv = psv[f*64+lane];
            Ais += af*wis; Aiv0 += a0f*wiv; Aiv1 += a1f*wiv; Aiv2 += a2f*wiv;
            scs += sf*wss; scv0 += w0f*wsv; scv1 += w1f*wsv; scv2 += w2f*wsv;
        }
        Ais *= kINV_AVG; Aiv0 *= kINV_AVG; Aiv1 *= kINV_AVG; Aiv2 *= kINV_AVG;
        float d = Aiv0*Aiv0 + Aiv1*Aiv1 + Aiv2*Aiv2;
        const float* pw = wps + spec*5*64;
        const float* pu = wpv + spec*4*64;
        float w0 = pw[0*64+lane], w1 = pw[1*64+lane], w2 = pw[2*64+lane];
        float w3 = pw[3*64+lane], w4 = pw[4*64+lane];
        float u0 = pu[0*64+lane], u1 = pu[1*64+lane];
        float u2 = pu[2*64+lane], u3 = pu[3*64+lane];
        float as2 = Ais*Ais;
        float Bs = w0*Ais + w1*as2 + w2*d + w3*as2*Ais + w4*Ais*d;
        float g  = u0 + u1*Ais + u2*as2 + u3*d;
        float Bv0 = g*Aiv0, Bv1 = g*Aiv1, Bv2 = g*Aiv2;
        float so=0.f, vo0=0.f, vo1=0.f, vo2=0.f;
        #pragma unroll 16
        for (int f=0; f<64; ++f){
            float bsf = __shfl(Bs, f);
            float bv0f = __shfl(Bv0,f), bv1f = __shfl(Bv1,f), bv2f = __shfl(Bv2,f);
            float wp = b2f(lWps[f*64+lane]), wv = b2f(lWpv[f*64+lane]);
            so += bsf*wp; vo0 += bv0f*wv; vo1 += bv1f*wv; vo2 += bv2f*wv;
        }
        so  += scs;
        vo0 += scv0; vo1 += scv1; vo2 += scv2;
        out_s[n*64+lane] = so;
        out_v[(n*64+lane)*3+0] = vo0;
        out_v[(n*64+lane)*3+1] = vo1;
        out_v[(n*64+lane)*3+2] = vo2;
        float r = so * Wread[lane];
        #pragma unroll
        for (int off=32; off>0; off>>=1) r += __shfl_xor(r, off);
        if (lane == 0) out_node[n] = r;
    }
}

extern "C" void kernel_launch(void* const* d_in, const int* in_sizes, int n_in,
                              void* d_out, int out_size, void* d_ws, size_t ws_size,
                              hipStream_t stream)
{
    (void)in_sizes; (void)n_in; (void)out_size; (void)ws_size;
    const float* s    = (const float*)d_in[0];
    const float* v    = (const float*)d_in[1];
    const float* Y1   = (const float*)d_in[2];
    const float* ef   = (const float*)d_in[3];
    const int* specie = (const int*)d_in[4];
    const int* senders   = (const int*)d_in[5];
    const int* receivers = (const int*)d_in[6];
    const float* Wls  = (const float*)d_in[7];
    const float* Wlv  = (const float*)d_in[8];
    const float* Wss  = (const float*)d_in[9];
    const float* Wsv  = (const float*)d_in[10];
    const float* Wr1  = (const float*)d_in[11];
    const float* Wr2  = (const float*)d_in[12];
    const float* Wis  = (const float*)d_in[13];
    const float* Wiv  = (const float*)d_in[14];
    const float* wps  = (const float*)d_in[15];
    const float* wpv  = (const float*)d_in[16];
    const float* Wps  = (const float*)d_in[17];
    const float* Wpv  = (const float*)d_in[18];
    const float* Wrd  = (const float*)d_in[19];

    float* out = (float*)d_out;
    float* As  = out + NNODES;              // [N,64]  fp32 accumulator (aliases s_out)
    float* Av  = out + NNODES + NNODES*64;  // [N,3,64] fp32 accumulator (aliases v_out)

    // workspace: [0,40960) W2 B-fragments bf16; [64K, 64K+10.24M) s1/v1 bf16
    unsigned short* W2s  = (unsigned short*)d_ws;
    unsigned short* t_s1 = (unsigned short*)((char*)d_ws + 65536);
    unsigned short* t_v1 = t_s1 + NNODES*64;

    hipMemsetAsync(As, 0, (size_t)NNODES*(64+192)*4, stream);
    kprepW2<<<1, 256, 0, stream>>>(Wr2, W2s);
    knodeA<<<1250, 256, 0, stream>>>(s, v, Wls, Wlv, t_s1, t_v1);
    kedge2<<<5000, 256, 0, stream>>>(Y1, ef, senders, receivers, Wr1, W2s, t_s1, t_v1, As, Av);
    knodeC<<<1250, 256, 0, stream>>>(specie, s, v, Wis, Wiv, Wss, Wsv,
                                     wps, wpv, Wps, Wpv, Wrd, out);
}

// Round 5
// 527.620 us; speedup vs baseline: 1.6862x; 1.2088x over previous
//
#include <hip/hip_runtime.h>

// MACE layer, fp32 I/O. N=20000, E=320000, F=64, P=5, R=8, H=64, S=10.
// R5: atomic scatter switched to packed-fp16 atomics (global_atomic_pk_add_f16):
//   Ah [N][2][64] half2 in ws -- pair0=(ms,mv0), pair1=(mv1,mv2) per channel.
//   2 dword-atomics/edge/channel-row instead of 4 (atomic-throughput bound at
//   ~300G lane-atomics/s per R4 counters).
// bf16 s1/v1 temporaries now live in d_out's s/v region (knodeA writes, kedge2
// reads, knodeC fully overwrites -- sequential stream, no hazard).
#define NNODES 20000
#define NEDGES 320000

typedef __attribute__((ext_vector_type(8))) short short8;    // 8 bf16 (4 VGPRs)
typedef __attribute__((ext_vector_type(4))) float float4v;   // MFMA acc
typedef _Float16 half2v __attribute__((ext_vector_type(2))); // packed fp16 pair

__device__ __forceinline__ float bitsf(unsigned u){ union{unsigned u; float f;} x; x.u=u; return x.f; }
__device__ __forceinline__ float b2f(unsigned short u){ return bitsf(((unsigned)u)<<16); }
__device__ __forceinline__ unsigned short f2b(float f){
    union{float f; unsigned u;} x; x.f=f;
    unsigned r = x.u + 0x7fffu + ((x.u>>16)&1u);   // RNE
    return (unsigned short)(r>>16);
}

__constant__ float kINV_SQRT3 = 0.5773502691896258f;
__constant__ float kINV_SQRT2 = 0.7071067811865476f;
__constant__ float kINV_AVG   = 0.25f;             // 1/sqrt(16)

// ---- Pre-kernel: swizzle W_rad2 [64][320] fp32 -> bf16 B-fragments ----------------------
__global__ void kprepW2(const float* __restrict__ Wr2, unsigned short* __restrict__ W2s)
{
    for (int c = threadIdx.x; c < 2560; c += 256){
        const int nt = c >> 7, ks = (c >> 6) & 1, ln = c & 63;
        const int col = nt*16 + (ln & 15);
        const int jb  = ks*32 + ((ln >> 4) & 3)*8;
        unsigned short t[8];
        #pragma unroll
        for (int jj = 0; jj < 8; ++jj) t[jj] = f2b(Wr2[(jb+jj)*320 + col]);
        unsigned* d = (unsigned*)(W2s + c*8);
        d[0] = (unsigned)t[0] | ((unsigned)t[1]<<16);
        d[1] = (unsigned)t[2] | ((unsigned)t[3]<<16);
        d[2] = (unsigned)t[4] | ((unsigned)t[5]<<16);
        d[3] = (unsigned)t[6] | ((unsigned)t[7]<<16);
    }
}

// ---------------- Kernel A: s1 = s@W_lin_s ; v1 = v@W_lin_v (bf16 into d_out temp) -------
__global__ __launch_bounds__(256) void knodeA(
    const float* __restrict__ s, const float* __restrict__ v,
    const float* __restrict__ Wls, const float* __restrict__ Wlv,
    unsigned short* __restrict__ s1, unsigned short* __restrict__ v1)
{
    __shared__ float lWls[4096], lWlv[4096];
    for (int i = threadIdx.x; i < 4096; i += 256){ lWls[i] = Wls[i]; lWlv[i] = Wlv[i]; }
    __syncthreads();
    const int lane = threadIdx.x & 63;
    const int wave = threadIdx.x >> 6;
    for (int it = 0; it < 4; ++it){
        const int n = blockIdx.x * 16 + it * 4 + wave;
        float sv  = s[n*64 + lane];
        float v0  = v[(n*64 + lane)*3 + 0];
        float v1r = v[(n*64 + lane)*3 + 1];
        float v2r = v[(n*64 + lane)*3 + 2];
        float a_s=0.f, a0=0.f, a1=0.f, a2=0.f;
        #pragma unroll 16
        for (int f = 0; f < 64; ++f){
            float sf  = __shfl(sv, f);
            float vf0 = __shfl(v0, f), vf1 = __shfl(v1r, f), vf2 = __shfl(v2r, f);
            float wls = lWls[f*64 + lane], wlv = lWlv[f*64 + lane];
            a_s += sf*wls; a0 += vf0*wlv; a1 += vf1*wlv; a2 += vf2*wlv;
        }
        s1[n*64+lane] = f2b(a_s);
        v1[(n*3+0)*64+lane] = f2b(a0);
        v1[(n*3+1)*64+lane] = f2b(a1);
        v1[(n*3+2)*64+lane] = f2b(a2);
    }
}

// ---- Kernel B: layer1 -> MFMA tw-GEMM -> TP -> packed-fp16 atomic scatter ---------------
__global__ __launch_bounds__(256) void kedge2(
    const float* __restrict__ Y1, const float* __restrict__ ef,
    const int* __restrict__ senders, const int* __restrict__ receivers,
    const float* __restrict__ Wr1, const unsigned short* __restrict__ W2s,
    const unsigned short* __restrict__ s1, const unsigned short* __restrict__ v1,
    half2v* __restrict__ Ah)
{
    __shared__ unsigned short hlds[64*72];    // h tile, stride 72 bf16
    __shared__ unsigned short twlds[64*330];  // tw tile, stride 330 bf16
    const int lane = threadIdx.x & 63;
    const int w    = threadIdx.x >> 6;
    const int ew   = blockIdx.x*64 + w*16;    // this wave's first edge

    // ---- stage: per-wave edge metadata + radial layer 1 ----
    float ef0 = ef[ew*8 + lane];              // edges ew..ew+7, r=lane&7
    float ef1 = ef[ew*8 + 64 + lane];         // edges ew+8..ew+15
    float w1r[8];
    #pragma unroll
    for (int r = 0; r < 8; ++r) w1r[r] = Wr1[r*64 + lane];
    float yreg  = (lane < 48) ? Y1[ew*3 + lane] : 0.f;
    int sndreg  = (lane < 16) ? senders[ew + lane]   : 0;
    int rcvreg  = (lane < 16) ? receivers[ew + lane] : 0;
    #pragma unroll
    for (int e16 = 0; e16 < 16; ++e16){
        float src = (e16 < 8) ? ef0 : ef1;
        float hj = 0.f;
        #pragma unroll
        for (int r = 0; r < 8; ++r) hj += __shfl(src, (e16&7)*8 + r) * w1r[r];
        hj = hj / (1.f + __expf(-hj));        // silu
        hlds[(w*16 + e16)*72 + lane] = f2b(hj);
    }
    __syncthreads();

    // ---- MFMA GEMM: tw[16 e][320] = h[16,64] @ W2[64,320] ----
    short8 a0 = *(const short8*)&hlds[(w*16 + (lane&15))*72 +      (lane>>4)*8];
    short8 a1 = *(const short8*)&hlds[(w*16 + (lane&15))*72 + 32 + (lane>>4)*8];
    float4v acc[20];
    #pragma unroll
    for (int nt = 0; nt < 20; ++nt){
        short8 b0 = *(const short8*)&W2s[((nt*2+0)*64 + lane)*8];
        short8 b1 = *(const short8*)&W2s[((nt*2+1)*64 + lane)*8];
        float4v z = {0.f, 0.f, 0.f, 0.f};
        acc[nt] = __builtin_amdgcn_mfma_f32_16x16x32_bf16(a0, b0, z, 0, 0, 0);
        acc[nt] = __builtin_amdgcn_mfma_f32_16x16x32_bf16(a1, b1, acc[nt], 0, 0, 0);
    }
    #pragma unroll
    for (int nt = 0; nt < 20; ++nt){
        const int col = nt*16 + (lane & 15);
        #pragma unroll
        for (int r = 0; r < 4; ++r){
            const int erow = w*16 + (lane>>4)*4 + r;
            twlds[erow*330 + col] = f2b(acc[nt][r]);
        }
    }

    // ---- TP + packed-fp16 atomic scatter: lane = channel f ----
    for (int e16 = 0; e16 < 16; ++e16){
        const int erow = w*16 + e16;
        float tw0 = b2f(twlds[erow*330 +   0 + lane]);
        float tw1 = b2f(twlds[erow*330 +  64 + lane]);
        float tw2 = b2f(twlds[erow*330 + 128 + lane]);
        float tw3 = b2f(twlds[erow*330 + 192 + lane]);
        float tw4 = b2f(twlds[erow*330 + 256 + lane]);
        const int snd = __shfl(sndreg, e16);
        const int rcv = __shfl(rcvreg, e16);
        float y0 = __shfl(yreg, e16*3+0);
        float y1 = __shfl(yreg, e16*3+1);
        float y2 = __shfl(yreg, e16*3+2);
        float ss  = b2f(s1[snd*64 + lane]);
        float vs0 = b2f(v1[(snd*3+0)*64 + lane]);
        float vs1 = b2f(v1[(snd*3+1)*64 + lane]);
        float vs2 = b2f(v1[(snd*3+2)*64 + lane]);
        float dot = vs0*y0 + vs1*y1 + vs2*y2;
        float c0 = vs1*y2 - vs2*y1;
        float c1 = vs2*y0 - vs0*y2;
        float c2 = vs0*y1 - vs1*y0;
        float ms  = tw0*ss + tw1*dot*kINV_SQRT3;
        float t2s = tw2*ss, t4 = tw4*kINV_SQRT2;
        float mv0 = t2s*y0 + tw3*vs0 + t4*c0;
        float mv1 = t2s*y1 + tw3*vs1 + t4*c1;
        float mv2 = t2s*y2 + tw3*vs2 + t4*c2;
        half2v p01 = { (_Float16)ms,  (_Float16)mv0 };
        half2v p23 = { (_Float16)mv1, (_Float16)mv2 };
        __builtin_amdgcn_global_atomic_fadd_v2f16(&Ah[rcv*128 + lane],      p01);
        __builtin_amdgcn_global_atomic_fadd_v2f16(&Ah[rcv*128 + 64 + lane], p23);
    }
}

// ---- Kernel C: W_int, product basis, W_prod, species skip (recomputed), readout ----------
__global__ __launch_bounds__(256) void knodeC(
    const int* __restrict__ specie,
    const float* __restrict__ s, const float* __restrict__ v,
    const half2v* __restrict__ Ah,
    const float* __restrict__ Wis, const float* __restrict__ Wiv,
    const float* __restrict__ Wss, const float* __restrict__ Wsv,
    const float* __restrict__ wps, const float* __restrict__ wpv,
    const float* __restrict__ Wps, const float* __restrict__ Wpv,
    const float* __restrict__ Wread,
    float* __restrict__ out)
{
    __shared__ float lWis[4096], lWiv[4096];
    __shared__ unsigned short lWps[4096], lWpv[4096];
    for (int i = threadIdx.x; i < 4096; i += 256){
        lWis[i] = Wis[i]; lWiv[i] = Wiv[i];
        lWps[i] = f2b(Wps[i]); lWpv[i] = f2b(Wpv[i]);
    }
    __syncthreads();
    const int lane = threadIdx.x & 63;
    const int wave = threadIdx.x >> 6;
    float* out_node = out;
    float* out_s    = out + NNODES;
    float* out_v    = out + NNODES + NNODES*64;
    for (int it = 0; it < 4; ++it){
        const int n = blockIdx.x*16 + it*4 + wave;
        half2v p01 = Ah[n*128 + lane];
        half2v p23 = Ah[n*128 + 64 + lane];
        float as  = (float)p01.x;
        float av0 = (float)p01.y;
        float av1 = (float)p23.x;
        float av2 = (float)p23.y;
        float sv  = s[n*64 + lane];
        float vv0 = v[(n*64 + lane)*3 + 0];
        float vv1 = v[(n*64 + lane)*3 + 1];
        float vv2 = v[(n*64 + lane)*3 + 2];
        const int spec = specie[n];
        const float* pss = Wss + spec*4096;
        const float* psv = Wsv + spec*4096;
        float Ais=0.f, Aiv0=0.f, Aiv1=0.f, Aiv2=0.f;
        float scs=0.f, scv0=0.f, scv1=0.f, scv2=0.f;
        #pragma unroll 8
        for (int f=0; f<64; ++f){
            float af  = __shfl(as, f);
            float a0f = __shfl(av0,f), a1f = __shfl(av1,f), a2f = __shfl(av2,f);
            float sf  = __shfl(sv, f);
            float w0f = __shfl(vv0,f), w1f = __shfl(vv1,f), w2f = __shfl(vv2,f);
            float wis = lWis[f*64+lane], wiv = lWiv[f*64+lane];
            float wss = pss[f*64+lane], wsv = psv[f*64+lane];
            Ais += af*wis; Aiv0 += a0f*wiv; Aiv1 += a1f*wiv; Aiv2 += a2f*wiv;
            scs += sf*wss; scv0 += w0f*wsv; scv1 += w1f*wsv; scv2 += w2f*wsv;
        }
        Ais *= kINV_AVG; Aiv0 *= kINV_AVG; Aiv1 *= kINV_AVG; Aiv2 *= kINV_AVG;
        float d = Aiv0*Aiv0 + Aiv1*Aiv1 + Aiv2*Aiv2;
        const float* pw = wps + spec*5*64;
        const float* pu = wpv + spec*4*64;
        float w0 = pw[0*64+lane], w1 = pw[1*64+lane], w2 = pw[2*64+lane];
        float w3 = pw[3*64+lane], w4 = pw[4*64+lane];
        float u0 = pu[0*64+lane], u1 = pu[1*64+lane];
        float u2 = pu[2*64+lane], u3 = pu[3*64+lane];
        float as2 = Ais*Ais;
        float Bs = w0*Ais + w1*as2 + w2*d + w3*as2*Ais + w4*Ais*d;
        float g  = u0 + u1*Ais + u2*as2 + u3*d;
        float Bv0 = g*Aiv0, Bv1 = g*Aiv1, Bv2 = g*Aiv2;
        float so=0.f, vo0=0.f, vo1=0.f, vo2=0.f;
        #pragma unroll 16
        for (int f=0; f<64; ++f){
            float bsf = __shfl(Bs, f);
            float bv0f = __shfl(Bv0,f), bv1f = __shfl(Bv1,f), bv2f = __shfl(Bv2,f);
            float wp = b2f(lWps[f*64+lane]), wv = b2f(lWpv[f*64+lane]);
            so += bsf*wp; vo0 += bv0f*wv; vo1 += bv1f*wv; vo2 += bv2f*wv;
        }
        so  += scs;
        vo0 += scv0; vo1 += scv1; vo2 += scv2;
        out_s[n*64+lane] = so;
        out_v[(n*64+lane)*3+0] = vo0;
        out_v[(n*64+lane)*3+1] = vo1;
        out_v[(n*64+lane)*3+2] = vo2;
        float r = so * Wread[lane];
        #pragma unroll
        for (int off=32; off>0; off>>=1) r += __shfl_xor(r, off);
        if (lane == 0) out_node[n] = r;
    }
}

extern "C" void kernel_launch(void* const* d_in, const int* in_sizes, int n_in,
                              void* d_out, int out_size, void* d_ws, size_t ws_size,
                              hipStream_t stream)
{
    (void)in_sizes; (void)n_in; (void)out_size; (void)ws_size;
    const float* s    = (const float*)d_in[0];
    const float* v    = (const float*)d_in[1];
    const float* Y1   = (const float*)d_in[2];
    const float* ef   = (const float*)d_in[3];
    const int* specie = (const int*)d_in[4];
    const int* senders   = (const int*)d_in[5];
    const int* receivers = (const int*)d_in[6];
    const float* Wls  = (const float*)d_in[7];
    const float* Wlv  = (const float*)d_in[8];
    const float* Wss  = (const float*)d_in[9];
    const float* Wsv  = (const float*)d_in[10];
    const float* Wr1  = (const float*)d_in[11];
    const float* Wr2  = (const float*)d_in[12];
    const float* Wis  = (const float*)d_in[13];
    const float* Wiv  = (const float*)d_in[14];
    const float* wps  = (const float*)d_in[15];
    const float* wpv  = (const float*)d_in[16];
    const float* Wps  = (const float*)d_in[17];
    const float* Wpv  = (const float*)d_in[18];
    const float* Wrd  = (const float*)d_in[19];

    float* out = (float*)d_out;

    // bf16 s1/v1 temporaries live in d_out's s/v region (10.24 MB of the 20.48 MB):
    unsigned short* t_s1 = (unsigned short*)(out + NNODES);   // [N*64] u16
    unsigned short* t_v1 = t_s1 + NNODES*64;                  // [N*192] u16

    // workspace: [0,64K) W2 B-fragments bf16; [64K, 64K+10.24M) Ah fp16 accumulator
    unsigned short* W2s = (unsigned short*)d_ws;
    half2v* Ah = (half2v*)((char*)d_ws + 65536);              // [N][2][64] half2

    hipMemsetAsync(Ah, 0, (size_t)NNODES*128*4, stream);      // fp16 +0 == 0x0000
    kprepW2<<<1, 256, 0, stream>>>(Wr2, W2s);
    knodeA<<<1250, 256, 0, stream>>>(s, v, Wls, Wlv, t_s1, t_v1);
    kedge2<<<5000, 256, 0, stream>>>(Y1, ef, senders, receivers, Wr1, W2s, t_s1, t_v1, Ah);
    knodeC<<<1250, 256, 0, stream>>>(specie, s, v, Ah, Wis, Wiv, Wss, Wsv,
                                     wps, wpv, Wps, Wpv, Wrd, out);
}

// Round 6
// 470.188 us; speedup vs baseline: 1.8921x; 1.1221x over previous
//
#include <hip/hip_runtime.h>

// MACE layer, fp32 I/O. N=20000, E=320000, F=64, P=5, R=8, H=64, S=10.
// R6: node kernels rewritten as MFMA GEMMs.
//  - All 64x64 weights pre-swizzled (kswz) to bf16 B-fragment layout in ws.
//  - knodeC2 uses species bucket-sort (khist/koff/kfill) -> 16-node tiles of
//    uniform species so the species skip is a per-tile GEMM. Dummy rows
//    (perm=-1) have zero A-frags and masked stores.
//  - kedge2 (MFMA tw-GEMM + packed-fp16 atomics) unchanged from R5.
#define NNODES 20000
#define NEDGES 320000
#define NTILES 1260          // ceil per-species-padded 20000/16 upper bound

typedef __attribute__((ext_vector_type(8))) short short8;    // 8 bf16
typedef __attribute__((ext_vector_type(4))) float float4v;   // MFMA acc
typedef _Float16 half2v __attribute__((ext_vector_type(2))); // packed fp16

// fragment-pool chunk offsets (1 chunk = 8 bf16 = 16 B)
#define CW2   0
#define CWls  2560
#define CWlv  3072
#define CWis  3584
#define CWiv  4096
#define CWps  4608
#define CWpv  5120
#define CWss  5632
#define CWsv  10752

__device__ __forceinline__ float bitsf(unsigned u){ union{unsigned u; float f;} x; x.u=u; return x.f; }
__device__ __forceinline__ float b2f(unsigned short u){ return bitsf(((unsigned)u)<<16); }
__device__ __forceinline__ unsigned short f2b(float f){
    union{float f; unsigned u;} x; x.f=f;
    unsigned r = x.u + 0x7fffu + ((x.u>>16)&1u);   // RNE
    return (unsigned short)(r>>16);
}
__device__ __forceinline__ short8 pack8(const float* f){
    short8 r;
    #pragma unroll
    for (int j=0;j<8;++j) r[j] = (short)f2b(f[j]);
    return r;
}

__constant__ float kINV_SQRT3 = 0.5773502691896258f;
__constant__ float kINV_SQRT2 = 0.7071067811865476f;
__constant__ float kINV_AVG   = 0.25f;             // 1/sqrt(16)

// ---- generic 64x64 (xS groups) fp32 -> bf16 B-fragment swizzle --------------------------
__global__ void kswz(const float* __restrict__ src, unsigned short* __restrict__ dst, int nchunks)
{
    for (int c = blockIdx.x*256 + threadIdx.x; c < nchunks; c += gridDim.x*256){
        const int grp = c >> 9;          // 512 chunks per 64x64 matrix
        const int loc = c & 511;
        const int nt = loc >> 7, ks = (loc >> 6) & 1, ln = loc & 63;
        const int col  = nt*16 + (ln & 15);
        const int row0 = grp*64 + ks*32 + ((ln>>4)&3)*8;
        unsigned short t[8];
        #pragma unroll
        for (int jj = 0; jj < 8; ++jj) t[jj] = f2b(src[(row0+jj)*64 + col]);
        unsigned* d = (unsigned*)(dst + c*8);
        d[0] = (unsigned)t[0] | ((unsigned)t[1]<<16);
        d[1] = (unsigned)t[2] | ((unsigned)t[3]<<16);
        d[2] = (unsigned)t[4] | ((unsigned)t[5]<<16);
        d[3] = (unsigned)t[6] | ((unsigned)t[7]<<16);
    }
}

// ---- W_rad2 [64][320] fp32 -> bf16 B-fragments (row stride 320) -------------------------
__global__ void kprepW2(const float* __restrict__ Wr2, unsigned short* __restrict__ W2s)
{
    for (int c = blockIdx.x*256 + threadIdx.x; c < 2560; c += gridDim.x*256){
        const int nt = c >> 7, ks = (c >> 6) & 1, ln = c & 63;
        const int col = nt*16 + (ln & 15);
        const int jb  = ks*32 + ((ln >> 4) & 3)*8;
        unsigned short t[8];
        #pragma unroll
        for (int jj = 0; jj < 8; ++jj) t[jj] = f2b(Wr2[(jb+jj)*320 + col]);
        unsigned* d = (unsigned*)(W2s + c*8);
        d[0] = (unsigned)t[0] | ((unsigned)t[1]<<16);
        d[1] = (unsigned)t[2] | ((unsigned)t[3]<<16);
        d[2] = (unsigned)t[4] | ((unsigned)t[5]<<16);
        d[3] = (unsigned)t[6] | ((unsigned)t[7]<<16);
    }
}

// ---- species bucketing -------------------------------------------------------------------
__global__ void khist(const int* __restrict__ specie, int* __restrict__ counts){
    int n = blockIdx.x*256 + threadIdx.x;
    if (n < NNODES) atomicAdd(&counts[specie[n]], 1);
}
__global__ void koff(const int* __restrict__ counts, int* __restrict__ cursor, int* __restrict__ tspec){
    for (int t = threadIdx.x; t < NTILES; t += 256) tspec[t] = 0;
    __syncthreads();
    if (threadIdx.x == 0){
        int base = 0;
        for (int sp = 0; sp < 10; ++sp){
            cursor[sp] = base;
            int nt = (counts[sp] + 15) >> 4;
            int t0 = base >> 4;
            for (int t = 0; t < nt; ++t) tspec[t0 + t] = sp;
            base += nt*16;
        }
    }
}
__global__ void kfill(const int* __restrict__ specie, int* __restrict__ cursor, int* __restrict__ perm){
    int n = blockIdx.x*256 + threadIdx.x;
    if (n < NNODES){ int slot = atomicAdd(&cursor[specie[n]], 1); perm[slot] = n; }
}

// ---- Kernel A (MFMA): s1 = s@Wls, v1 = v@Wlv (bf16 into d_out temp) ---------------------
__global__ __launch_bounds__(256) void knodeA2(
    const float* __restrict__ s, const float* __restrict__ v,
    const unsigned short* __restrict__ P,
    unsigned short* __restrict__ s1, unsigned short* __restrict__ v1)
{
    const int w = threadIdx.x >> 6, lane = threadIdx.x & 63;
    const int t = blockIdx.x*4 + w;
    if (t >= 1250) return;
    const int mcol = lane & 15, quad = lane >> 4;
    const int node = t*16 + mcol;               // A-row node
    const short8* PB = (const short8*)P;

    short8 fS[2], fV[3][2];
    #pragma unroll
    for (int ks = 0; ks < 2; ++ks){
        const int k0 = ks*32 + quad*8;
        float tmp[8];
        #pragma unroll
        for (int j = 0; j < 8; ++j) tmp[j] = s[node*64 + k0 + j];
        fS[ks] = pack8(tmp);
        #pragma unroll
        for (int c = 0; c < 3; ++c){
            float tv[8];
            #pragma unroll
            for (int j = 0; j < 8; ++j) tv[j] = v[(node*64 + k0 + j)*3 + c];
            fV[c][ks] = pack8(tv);
        }
    }
    float4v z = {0.f,0.f,0.f,0.f};
    #pragma unroll
    for (int nt = 0; nt < 4; ++nt){
        float4v aS = __builtin_amdgcn_mfma_f32_16x16x32_bf16(fS[0], PB[CWls+(nt*2+0)*64+lane], z, 0,0,0);
        aS = __builtin_amdgcn_mfma_f32_16x16x32_bf16(fS[1], PB[CWls+(nt*2+1)*64+lane], aS, 0,0,0);
        float4v aV[3];
        #pragma unroll
        for (int c = 0; c < 3; ++c){
            aV[c] = __builtin_amdgcn_mfma_f32_16x16x32_bf16(fV[c][0], PB[CWlv+(nt*2+0)*64+lane], z, 0,0,0);
            aV[c] = __builtin_amdgcn_mfma_f32_16x16x32_bf16(fV[c][1], PB[CWlv+(nt*2+1)*64+lane], aV[c], 0,0,0);
        }
        const int g = nt*16 + mcol;
        #pragma unroll
        for (int r = 0; r < 4; ++r){
            const int nr = t*16 + quad*4 + r;   // C/D row node
            s1[nr*64 + g] = f2b(aS[r]);
            #pragma unroll
            for (int c = 0; c < 3; ++c) v1[(nr*3+c)*64 + g] = f2b(aV[c][r]);
        }
    }
}

// ---- Kernel B: layer1 -> MFMA tw-GEMM -> TP -> packed-fp16 atomic scatter ---------------
__global__ __launch_bounds__(256) void kedge2(
    const float* __restrict__ Y1, const float* __restrict__ ef,
    const int* __restrict__ senders, const int* __restrict__ receivers,
    const float* __restrict__ Wr1, const unsigned short* __restrict__ W2s,
    const unsigned short* __restrict__ s1, const unsigned short* __restrict__ v1,
    half2v* __restrict__ Ah)
{
    __shared__ unsigned short hlds[64*72];
    __shared__ unsigned short twlds[64*330];
    const int lane = threadIdx.x & 63;
    const int w    = threadIdx.x >> 6;
    const int ew   = blockIdx.x*64 + w*16;

    float ef0 = ef[ew*8 + lane];
    float ef1 = ef[ew*8 + 64 + lane];
    float w1r[8];
    #pragma unroll
    for (int r = 0; r < 8; ++r) w1r[r] = Wr1[r*64 + lane];
    float yreg  = (lane < 48) ? Y1[ew*3 + lane] : 0.f;
    int sndreg  = (lane < 16) ? senders[ew + lane]   : 0;
    int rcvreg  = (lane < 16) ? receivers[ew + lane] : 0;
    #pragma unroll
    for (int e16 = 0; e16 < 16; ++e16){
        float src = (e16 < 8) ? ef0 : ef1;
        float hj = 0.f;
        #pragma unroll
        for (int r = 0; r < 8; ++r) hj += __shfl(src, (e16&7)*8 + r) * w1r[r];
        hj = hj / (1.f + __expf(-hj));
        hlds[(w*16 + e16)*72 + lane] = f2b(hj);
    }
    __syncthreads();

    short8 a0 = *(const short8*)&hlds[(w*16 + (lane&15))*72 +      (lane>>4)*8];
    short8 a1 = *(const short8*)&hlds[(w*16 + (lane&15))*72 + 32 + (lane>>4)*8];
    float4v acc[20];
    #pragma unroll
    for (int nt = 0; nt < 20; ++nt){
        short8 b0 = *(const short8*)&W2s[((nt*2+0)*64 + lane)*8];
        short8 b1 = *(const short8*)&W2s[((nt*2+1)*64 + lane)*8];
        float4v z = {0.f, 0.f, 0.f, 0.f};
        acc[nt] = __builtin_amdgcn_mfma_f32_16x16x32_bf16(a0, b0, z, 0, 0, 0);
        acc[nt] = __builtin_amdgcn_mfma_f32_16x16x32_bf16(a1, b1, acc[nt], 0, 0, 0);
    }
    #pragma unroll
    for (int nt = 0; nt < 20; ++nt){
        const int col = nt*16 + (lane & 15);
        #pragma unroll
        for (int r = 0; r < 4; ++r){
            const int erow = w*16 + (lane>>4)*4 + r;
            twlds[erow*330 + col] = f2b(acc[nt][r]);
        }
    }

    for (int e16 = 0; e16 < 16; ++e16){
        const int erow = w*16 + e16;
        float tw0 = b2f(twlds[erow*330 +   0 + lane]);
        float tw1 = b2f(twlds[erow*330 +  64 + lane]);
        float tw2 = b2f(twlds[erow*330 + 128 + lane]);
        float tw3 = b2f(twlds[erow*330 + 192 + lane]);
        float tw4 = b2f(twlds[erow*330 + 256 + lane]);
        const int snd = __shfl(sndreg, e16);
        const int rcv = __shfl(rcvreg, e16);
        float y0 = __shfl(yreg, e16*3+0);
        float y1 = __shfl(yreg, e16*3+1);
        float y2 = __shfl(yreg, e16*3+2);
        float ss  = b2f(s1[snd*64 + lane]);
        float vs0 = b2f(v1[(snd*3+0)*64 + lane]);
        float vs1 = b2f(v1[(snd*3+1)*64 + lane]);
        float vs2 = b2f(v1[(snd*3+2)*64 + lane]);
        float dot = vs0*y0 + vs1*y1 + vs2*y2;
        float c0 = vs1*y2 - vs2*y1;
        float c1 = vs2*y0 - vs0*y2;
        float c2 = vs0*y1 - vs1*y0;
        float ms  = tw0*ss + tw1*dot*kINV_SQRT3;
        float t2s = tw2*ss, t4 = tw4*kINV_SQRT2;
        float mv0 = t2s*y0 + tw3*vs0 + t4*c0;
        float mv1 = t2s*y1 + tw3*vs1 + t4*c1;
        float mv2 = t2s*y2 + tw3*vs2 + t4*c2;
        half2v p01 = { (_Float16)ms,  (_Float16)mv0 };
        half2v p23 = { (_Float16)mv1, (_Float16)mv2 };
        __builtin_amdgcn_global_atomic_fadd_v2f16(&Ah[rcv*128 + lane],      p01);
        __builtin_amdgcn_global_atomic_fadd_v2f16(&Ah[rcv*128 + 64 + lane], p23);
    }
}

// ---- Kernel C (MFMA, species-sorted tiles) ----------------------------------------------
__global__ __launch_bounds__(256) void knodeC2(
    const float* __restrict__ s, const float* __restrict__ v,
    const half2v* __restrict__ Ah,
    const unsigned short* __restrict__ P,
    const int* __restrict__ perm, const int* __restrict__ tspec,
    const float* __restrict__ wps, const float* __restrict__ wpv,
    const float* __restrict__ Wread,
    float* __restrict__ out)
{
    __shared__ unsigned short Bt[4][4][16*72];    // [wave][mat: Bs,Bv0,Bv1,Bv2]
    const int w = threadIdx.x >> 6, lane = threadIdx.x & 63;
    const int t = blockIdx.x*4 + w;
    if (t >= NTILES) return;
    const int mcol = lane & 15, quad = lane >> 4;
    const int spec = tspec[t];
    const int nA   = perm[t*16 + mcol];           // A-row node (may be -1)
    const short8* PB = (const short8*)P;
    const int sb = CWss + spec*512, vb = CWsv + spec*512;

    // ---- build A-frags: A_s/A_v from Ah (fp16), skip inputs from s/v (fp32) ----
    short8 fAs[2], fAv[3][2], fS[2], fV[3][2];
    if (nA >= 0){
        #pragma unroll
        for (int ks = 0; ks < 2; ++ks){
            const int k0 = ks*32 + quad*8;
            float as_[8], a0_[8], a1_[8], a2_[8], ts[8], tv0[8], tv1[8], tv2[8];
            #pragma unroll
            for (int j = 0; j < 8; ++j){
                half2v p0 = Ah[nA*128 +      k0 + j];
                half2v p1 = Ah[nA*128 + 64 + k0 + j];
                as_[j] = (float)p0.x; a0_[j] = (float)p0.y;
                a1_[j] = (float)p1.x; a2_[j] = (float)p1.y;
                ts[j]  = s[nA*64 + k0 + j];
                tv0[j] = v[(nA*64 + k0 + j)*3 + 0];
                tv1[j] = v[(nA*64 + k0 + j)*3 + 1];
                tv2[j] = v[(nA*64 + k0 + j)*3 + 2];
            }
            fAs[ks] = pack8(as_); fAv[0][ks] = pack8(a0_);
            fAv[1][ks] = pack8(a1_); fAv[2][ks] = pack8(a2_);
            fS[ks] = pack8(ts); fV[0][ks] = pack8(tv0);
            fV[1][ks] = pack8(tv1); fV[2][ks] = pack8(tv2);
        }
    } else {
        short8 z8 = {};
        #pragma unroll
        for (int ks = 0; ks < 2; ++ks){
            fAs[ks] = z8; fS[ks] = z8;
            #pragma unroll
            for (int c = 0; c < 3; ++c){ fAv[c][ks] = z8; fV[c][ks] = z8; }
        }
    }

    // ---- phase 1: W_int matmuls + species skip matmuls; product basis -> LDS ----
    float4v z = {0.f,0.f,0.f,0.f};
    float4v scS[4], scV[3][4];
    #pragma unroll
    for (int nt = 0; nt < 4; ++nt){
        float4v Ais = __builtin_amdgcn_mfma_f32_16x16x32_bf16(fAs[0], PB[CWis+(nt*2+0)*64+lane], z, 0,0,0);
        Ais = __builtin_amdgcn_mfma_f32_16x16x32_bf16(fAs[1], PB[CWis+(nt*2+1)*64+lane], Ais, 0,0,0);
        float4v Aiv[3];
        #pragma unroll
        for (int c = 0; c < 3; ++c){
            Aiv[c] = __builtin_amdgcn_mfma_f32_16x16x32_bf16(fAv[c][0], PB[CWiv+(nt*2+0)*64+lane], z, 0,0,0);
            Aiv[c] = __builtin_amdgcn_mfma_f32_16x16x32_bf16(fAv[c][1], PB[CWiv+(nt*2+1)*64+lane], Aiv[c], 0,0,0);
        }
        scS[nt] = __builtin_amdgcn_mfma_f32_16x16x32_bf16(fS[0], PB[sb+(nt*2+0)*64+lane], z, 0,0,0);
        scS[nt] = __builtin_amdgcn_mfma_f32_16x16x32_bf16(fS[1], PB[sb+(nt*2+1)*64+lane], scS[nt], 0,0,0);
        #pragma unroll
        for (int c = 0; c < 3; ++c){
            scV[c][nt] = __builtin_amdgcn_mfma_f32_16x16x32_bf16(fV[c][0], PB[vb+(nt*2+0)*64+lane], z, 0,0,0);
            scV[c][nt] = __builtin_amdgcn_mfma_f32_16x16x32_bf16(fV[c][1], PB[vb+(nt*2+1)*64+lane], scV[c][nt], 0,0,0);
        }
        // elementwise product basis (C/D layout: row=quad*4+r, col g=nt*16+mcol)
        const int g = nt*16 + mcol;
        float w0 = wps[spec*320 +   0 + g], w1 = wps[spec*320 +  64 + g];
        float w2 = wps[spec*320 + 128 + g], w3 = wps[spec*320 + 192 + g];
        float w4 = wps[spec*320 + 256 + g];
        float u0 = wpv[spec*256 +   0 + g], u1 = wpv[spec*256 +  64 + g];
        float u2 = wpv[spec*256 + 128 + g], u3 = wpv[spec*256 + 192 + g];
        #pragma unroll
        for (int r = 0; r < 4; ++r){
            float A  = Ais[r]    * kINV_AVG;
            float a0 = Aiv[0][r] * kINV_AVG;
            float a1 = Aiv[1][r] * kINV_AVG;
            float a2 = Aiv[2][r] * kINV_AVG;
            float d   = a0*a0 + a1*a1 + a2*a2;
            float as2 = A*A;
            float Bs  = w0*A + w1*as2 + w2*d + w3*as2*A + w4*A*d;
            float gg  = u0 + u1*A + u2*as2 + u3*d;
            const int row = quad*4 + r;
            Bt[w][0][row*72 + g] = f2b(Bs);
            Bt[w][1][row*72 + g] = f2b(gg*a0);
            Bt[w][2][row*72 + g] = f2b(gg*a1);
            Bt[w][3][row*72 + g] = f2b(gg*a2);
        }
    }

    // ---- re-read B tiles as A-frags (same wave wrote them; no barrier needed) ----
    short8 bS[2], bV[3][2];
    #pragma unroll
    for (int ks = 0; ks < 2; ++ks){
        bS[ks] = *(const short8*)&Bt[w][0][mcol*72 + ks*32 + quad*8];
        #pragma unroll
        for (int c = 0; c < 3; ++c)
            bV[c][ks] = *(const short8*)&Bt[w][1+c][mcol*72 + ks*32 + quad*8];
    }

    // ---- phase 2: W_prod matmuls seeded with skip acc; stores + fused readout ----
    float* out_node = out;
    float* out_s    = out + NNODES;
    float* out_v    = out + NNODES + NNODES*64;
    int ndr[4];
    #pragma unroll
    for (int r = 0; r < 4; ++r) ndr[r] = perm[t*16 + quad*4 + r];
    float4v rd = {0.f,0.f,0.f,0.f};
    #pragma unroll
    for (int nt = 0; nt < 4; ++nt){
        float4v oS = scS[nt];
        oS = __builtin_amdgcn_mfma_f32_16x16x32_bf16(bS[0], PB[CWps+(nt*2+0)*64+lane], oS, 0,0,0);
        oS = __builtin_amdgcn_mfma_f32_16x16x32_bf16(bS[1], PB[CWps+(nt*2+1)*64+lane], oS, 0,0,0);
        float4v oV[3];
        #pragma unroll
        for (int c = 0; c < 3; ++c){
            oV[c] = scV[c][nt];
            oV[c] = __builtin_amdgcn_mfma_f32_16x16x32_bf16(bV[c][0], PB[CWpv+(nt*2+0)*64+lane], oV[c], 0,0,0);
            oV[c] = __builtin_amdgcn_mfma_f32_16x16x32_bf16(bV[c][1], PB[CWpv+(nt*2+1)*64+lane], oV[c], 0,0,0);
        }
        const int g = nt*16 + mcol;
        float wr = Wread[g];
        #pragma unroll
        for (int r = 0; r < 4; ++r){
            if (ndr[r] >= 0){
                out_s[ndr[r]*64 + g] = oS[r];
                #pragma unroll
                for (int c = 0; c < 3; ++c) out_v[(ndr[r]*64 + g)*3 + c] = oV[c][r];
            }
            rd[r] += oS[r] * wr;
        }
    }
    #pragma unroll
    for (int off = 1; off < 16; off <<= 1){
        #pragma unroll
        for (int r = 0; r < 4; ++r) rd[r] += __shfl_xor(rd[r], off);
    }
    if (mcol == 0){
        #pragma unroll
        for (int r = 0; r < 4; ++r) if (ndr[r] >= 0) out_node[ndr[r]] = rd[r];
    }
}

extern "C" void kernel_launch(void* const* d_in, const int* in_sizes, int n_in,
                              void* d_out, int out_size, void* d_ws, size_t ws_size,
                              hipStream_t stream)
{
    (void)in_sizes; (void)n_in; (void)out_size; (void)ws_size;
    const float* s    = (const float*)d_in[0];
    const float* v    = (const float*)d_in[1];
    const float* Y1   = (const float*)d_in[2];
    const float* ef   = (const float*)d_in[3];
    const int* specie = (const int*)d_in[4];
    const int* senders   = (const int*)d_in[5];
    const int* receivers = (const int*)d_in[6];
    const float* Wls  = (const float*)d_in[7];
    const float* Wlv  = (const float*)d_in[8];
    const float* Wss  = (const float*)d_in[9];
    const float* Wsv  = (const float*)d_in[10];
    const float* Wr1  = (const float*)d_in[11];
    const float* Wr2  = (const float*)d_in[12];
    const float* Wis  = (const float*)d_in[13];
    const float* Wiv  = (const float*)d_in[14];
    const float* wps  = (const float*)d_in[15];
    const float* wpv  = (const float*)d_in[16];
    const float* Wps  = (const float*)d_in[17];
    const float* Wpv  = (const float*)d_in[18];
    const float* Wrd  = (const float*)d_in[19];

    float* out = (float*)d_out;
    unsigned short* t_s1 = (unsigned short*)(out + NNODES);   // bf16 temp in d_out
    unsigned short* t_v1 = t_s1 + NNODES*64;

    // ws layout:
    //  [0, 253952)            bf16 fragment pool P (chunks of 16 B, offsets CW*)
    //  [262144, +10.24M)      Ah fp16 accumulator [N][2][64] half2
    //  [10502144, +40)        counts[10]
    //  [10502184, +40)        cursor[10]
    //  [10502224, +80640)     perm[20160]
    //  [10582864, +5040)      tspec[1260]
    char* ws = (char*)d_ws;
    unsigned short* P = (unsigned short*)ws;
    half2v* Ah  = (half2v*)(ws + 262144);
    int* counts = (int*)(ws + 10502144);
    int* cursor = (int*)(ws + 10502184);
    int* perm   = (int*)(ws + 10502224);
    int* tspec  = (int*)(ws + 10582864);

    hipMemsetAsync(Ah, 0, (size_t)NNODES*128*4, stream);
    hipMemsetAsync(counts, 0, 80, stream);                 // counts + cursor
    hipMemsetAsync(perm, 0xFF, 20160*4, stream);           // -1
    // weight swizzles (all independent)
    kprepW2<<<10, 256, 0, stream>>>(Wr2, P + CW2*8);
    kswz<<<2, 256, 0, stream>>>(Wls, P + CWls*8, 512);
    kswz<<<2, 256, 0, stream>>>(Wlv, P + CWlv*8, 512);
    kswz<<<2, 256, 0, stream>>>(Wis, P + CWis*8, 512);
    kswz<<<2, 256, 0, stream>>>(Wiv, P + CWiv*8, 512);
    kswz<<<2, 256, 0, stream>>>(Wps, P + CWps*8, 512);
    kswz<<<2, 256, 0, stream>>>(Wpv, P + CWpv*8, 512);
    kswz<<<20, 256, 0, stream>>>(Wss, P + CWss*8, 5120);
    kswz<<<20, 256, 0, stream>>>(Wsv, P + CWsv*8, 5120);
    // species bucketing
    khist<<<79, 256, 0, stream>>>(specie, counts);
    koff<<<1, 256, 0, stream>>>(counts, cursor, tspec);
    kfill<<<79, 256, 0, stream>>>(specie, cursor, perm);
    // main pipeline
    knodeA2<<<313, 256, 0, stream>>>(s, v, P, t_s1, t_v1);
    kedge2<<<5000, 256, 0, stream>>>(Y1, ef, senders, receivers, Wr1, P + CW2*8, t_s1, t_v1, Ah);
    knodeC2<<<315, 256, 0, stream>>>(s, v, Ah, P, perm, tspec, wps, wpv, Wrd, out);
}

// Round 8
// 332.324 us; speedup vs baseline: 2.6771x; 1.4149x over previous
//
#include <hip/hip_runtime.h>

// MACE layer, fp32 I/O. N=20000, E=320000, F=64, P=5, R=8, H=64, S=10.
// R8 == R7 resubmitted (R7 bench failed at container level, not kernel level).
// Dispatch chain 4 launches:
//   kprep   : block 0 = species bucketing (single-block LDS histogram/cursor,
//             perm=-1 init, tspec fill); blocks 1..62 = all weight swizzles
//             (15872 fragment chunks, grid-strided).
//   knodeA2 : zeroes Ah (grid-stride float4) then s1/v1 MFMA GEMM.
//   kedge2  : MFMA tw-GEMM + packed-fp16 atomics (unchanged since R5).
//   knodeC2 : MFMA + species-sorted tiles; s/v/Ah gathers vectorized (float4).
#define NNODES 20000
#define NEDGES 320000
#define NTILES 1260

typedef __attribute__((ext_vector_type(8))) short short8;    // 8 bf16
typedef __attribute__((ext_vector_type(4))) float float4v;   // 16 B
typedef _Float16 half2v __attribute__((ext_vector_type(2))); // packed fp16

// fragment-pool chunk offsets (1 chunk = 8 bf16 = 16 B)
#define CW2   0
#define CWls  2560
#define CWlv  3072
#define CWis  3584
#define CWiv  4096
#define CWps  4608
#define CWpv  5120
#define CWss  5632
#define CWsv  10752
#define NCHUNK_TOT 15872     // 2560 + 6*512 + 2*5120

__device__ __forceinline__ float bitsf(unsigned u){ union{unsigned u; float f;} x; x.u=u; return x.f; }
__device__ __forceinline__ float b2f(unsigned short u){ return bitsf(((unsigned)u)<<16); }
__device__ __forceinline__ unsigned short f2b(float f){
    union{float f; unsigned u;} x; x.f=f;
    unsigned r = x.u + 0x7fffu + ((x.u>>16)&1u);   // RNE
    return (unsigned short)(r>>16);
}
__device__ __forceinline__ short8 pack8(const float* f){
    short8 r;
    #pragma unroll
    for (int j=0;j<8;++j) r[j] = (short)f2b(f[j]);
    return r;
}

__constant__ float kINV_SQRT3 = 0.5773502691896258f;
__constant__ float kINV_SQRT2 = 0.7071067811865476f;
__constant__ float kINV_AVG   = 0.25f;             // 1/sqrt(16)

// ---- merged prep: bucketing (block 0) + all weight swizzles (blocks 1..62) --------------
__global__ __launch_bounds__(256) void kprep(
    const int* __restrict__ specie,
    const float* __restrict__ Wr2,
    const float* __restrict__ Wls, const float* __restrict__ Wlv,
    const float* __restrict__ Wis, const float* __restrict__ Wiv,
    const float* __restrict__ Wps, const float* __restrict__ Wpv,
    const float* __restrict__ Wss, const float* __restrict__ Wsv,
    unsigned short* __restrict__ P,
    int* __restrict__ perm, int* __restrict__ tspec)
{
    const int tid = threadIdx.x;
    if (blockIdx.x == 0){
        __shared__ int cnt[10], base[10], ntl[10], cur[10];
        if (tid < 10) cnt[tid] = 0;
        __syncthreads();
        for (int n = tid; n < NNODES; n += 256) atomicAdd(&cnt[specie[n]], 1);
        __syncthreads();
        if (tid == 0){
            int b = 0;
            for (int sp = 0; sp < 10; ++sp){
                base[sp] = b; cur[sp] = b;
                ntl[sp] = (cnt[sp] + 15) >> 4;
                b += ntl[sp] << 4;
            }
        }
        __syncthreads();
        for (int i = tid; i < NTILES*16; i += 256) perm[i] = -1;
        for (int t = tid; t < NTILES; t += 256){
            int sp = 0;
            #pragma unroll
            for (int k = 0; k < 10; ++k)
                if (t >= (base[k] >> 4) && t < (base[k] >> 4) + ntl[k]) sp = k;
            tspec[t] = sp;
        }
        __syncthreads();
        for (int n = tid; n < NNODES; n += 256){
            int slot = atomicAdd(&cur[specie[n]], 1);
            perm[slot] = n;
        }
        return;
    }
    // swizzle blocks: 62 x 256 = 15872 chunks, one each
    const int c = (blockIdx.x - 1)*256 + tid;
    if (c >= NCHUNK_TOT) return;
    unsigned short t[8];
    if (c < 2560){
        const int nt = c >> 7, ks = (c >> 6) & 1, ln = c & 63;
        const int col = nt*16 + (ln & 15);
        const int jb  = ks*32 + ((ln >> 4) & 3)*8;
        #pragma unroll
        for (int jj = 0; jj < 8; ++jj) t[jj] = f2b(Wr2[(jb+jj)*320 + col]);
    } else {
        int c2 = c - 2560;
        const float* src;
        if      (c2 <  512){ src = Wls; }
        else if (c2 < 1024){ src = Wlv; c2 -= 512; }
        else if (c2 < 1536){ src = Wis; c2 -= 1024; }
        else if (c2 < 2048){ src = Wiv; c2 -= 1536; }
        else if (c2 < 2560){ src = Wps; c2 -= 2048; }
        else if (c2 < 3072){ src = Wpv; c2 -= 2560; }
        else if (c2 < 8192){ src = Wss; c2 -= 3072; }
        else               { src = Wsv; c2 -= 8192; }
        const int grp = c2 >> 9, loc = c2 & 511;
        const int nt = loc >> 7, ks = (loc >> 6) & 1, ln = loc & 63;
        const int col  = nt*16 + (ln & 15);
        const int row0 = grp*64 + ks*32 + ((ln>>4)&3)*8;
        #pragma unroll
        for (int jj = 0; jj < 8; ++jj) t[jj] = f2b(src[(row0+jj)*64 + col]);
    }
    unsigned* d = (unsigned*)(P + (size_t)c*8);
    d[0] = (unsigned)t[0] | ((unsigned)t[1]<<16);
    d[1] = (unsigned)t[2] | ((unsigned)t[3]<<16);
    d[2] = (unsigned)t[4] | ((unsigned)t[5]<<16);
    d[3] = (unsigned)t[6] | ((unsigned)t[7]<<16);
}

// ---- Kernel A (MFMA): zero Ah, then s1 = s@Wls, v1 = v@Wlv ------------------------------
__global__ __launch_bounds__(256) void knodeA2(
    const float* __restrict__ s, const float* __restrict__ v,
    const unsigned short* __restrict__ P,
    unsigned short* __restrict__ s1, unsigned short* __restrict__ v1,
    float4v* __restrict__ AhZ)
{
    // zero the fp16 accumulator (NNODES*128 dwords = 640000 float4)
    float4v zz = {0.f,0.f,0.f,0.f};
    for (int i = blockIdx.x*256 + threadIdx.x; i < NNODES*32; i += 313*256) AhZ[i] = zz;

    const int w = threadIdx.x >> 6, lane = threadIdx.x & 63;
    const int t = blockIdx.x*4 + w;
    if (t >= 1250) return;
    const int mcol = lane & 15, quad = lane >> 4;
    const int node = t*16 + mcol;
    const short8* PB = (const short8*)P;

    short8 fS[2], fV[3][2];
    #pragma unroll
    for (int ks = 0; ks < 2; ++ks){
        const int k0 = ks*32 + quad*8;
        float ts[8];
        { float4v a = *(const float4v*)&s[node*64 + k0];
          float4v b = *(const float4v*)&s[node*64 + k0 + 4];
          #pragma unroll
          for (int j = 0; j < 4; ++j){ ts[j] = a[j]; ts[4+j] = b[j]; } }
        fS[ks] = pack8(ts);
        float tv[24];
        #pragma unroll
        for (int q = 0; q < 6; ++q){
            float4v x = *(const float4v*)&v[(node*64 + k0)*3 + q*4];
            #pragma unroll
            for (int j = 0; j < 4; ++j) tv[q*4+j] = x[j];
        }
        #pragma unroll
        for (int c = 0; c < 3; ++c){
            float tc[8];
            #pragma unroll
            for (int j = 0; j < 8; ++j) tc[j] = tv[j*3 + c];
            fV[c][ks] = pack8(tc);
        }
    }
    float4v z = {0.f,0.f,0.f,0.f};
    #pragma unroll
    for (int nt = 0; nt < 4; ++nt){
        float4v aS = __builtin_amdgcn_mfma_f32_16x16x32_bf16(fS[0], PB[CWls+(nt*2+0)*64+lane], z, 0,0,0);
        aS = __builtin_amdgcn_mfma_f32_16x16x32_bf16(fS[1], PB[CWls+(nt*2+1)*64+lane], aS, 0,0,0);
        float4v aV[3];
        #pragma unroll
        for (int c = 0; c < 3; ++c){
            aV[c] = __builtin_amdgcn_mfma_f32_16x16x32_bf16(fV[c][0], PB[CWlv+(nt*2+0)*64+lane], z, 0,0,0);
            aV[c] = __builtin_amdgcn_mfma_f32_16x16x32_bf16(fV[c][1], PB[CWlv+(nt*2+1)*64+lane], aV[c], 0,0,0);
        }
        const int g = nt*16 + mcol;
        #pragma unroll
        for (int r = 0; r < 4; ++r){
            const int nr = t*16 + quad*4 + r;
            s1[nr*64 + g] = f2b(aS[r]);
            #pragma unroll
            for (int c = 0; c < 3; ++c) v1[(nr*3+c)*64 + g] = f2b(aV[c][r]);
        }
    }
}

// ---- Kernel B: layer1 -> MFMA tw-GEMM -> TP -> packed-fp16 atomic scatter ---------------
__global__ __launch_bounds__(256) void kedge2(
    const float* __restrict__ Y1, const float* __restrict__ ef,
    const int* __restrict__ senders, const int* __restrict__ receivers,
    const float* __restrict__ Wr1, const unsigned short* __restrict__ W2s,
    const unsigned short* __restrict__ s1, const unsigned short* __restrict__ v1,
    half2v* __restrict__ Ah)
{
    __shared__ unsigned short hlds[64*72];
    __shared__ unsigned short twlds[64*330];
    const int lane = threadIdx.x & 63;
    const int w    = threadIdx.x >> 6;
    const int ew   = blockIdx.x*64 + w*16;

    float ef0 = ef[ew*8 + lane];
    float ef1 = ef[ew*8 + 64 + lane];
    float w1r[8];
    #pragma unroll
    for (int r = 0; r < 8; ++r) w1r[r] = Wr1[r*64 + lane];
    float yreg  = (lane < 48) ? Y1[ew*3 + lane] : 0.f;
    int sndreg  = (lane < 16) ? senders[ew + lane]   : 0;
    int rcvreg  = (lane < 16) ? receivers[ew + lane] : 0;
    #pragma unroll
    for (int e16 = 0; e16 < 16; ++e16){
        float src = (e16 < 8) ? ef0 : ef1;
        float hj = 0.f;
        #pragma unroll
        for (int r = 0; r < 8; ++r) hj += __shfl(src, (e16&7)*8 + r) * w1r[r];
        hj = hj / (1.f + __expf(-hj));
        hlds[(w*16 + e16)*72 + lane] = f2b(hj);
    }
    __syncthreads();

    short8 a0 = *(const short8*)&hlds[(w*16 + (lane&15))*72 +      (lane>>4)*8];
    short8 a1 = *(const short8*)&hlds[(w*16 + (lane&15))*72 + 32 + (lane>>4)*8];
    float4v acc[20];
    #pragma unroll
    for (int nt = 0; nt < 20; ++nt){
        short8 b0 = *(const short8*)&W2s[((nt*2+0)*64 + lane)*8];
        short8 b1 = *(const short8*)&W2s[((nt*2+1)*64 + lane)*8];
        float4v z = {0.f, 0.f, 0.f, 0.f};
        acc[nt] = __builtin_amdgcn_mfma_f32_16x16x32_bf16(a0, b0, z, 0, 0, 0);
        acc[nt] = __builtin_amdgcn_mfma_f32_16x16x32_bf16(a1, b1, acc[nt], 0, 0, 0);
    }
    #pragma unroll
    for (int nt = 0; nt < 20; ++nt){
        const int col = nt*16 + (lane & 15);
        #pragma unroll
        for (int r = 0; r < 4; ++r){
            const int erow = w*16 + (lane>>4)*4 + r;
            twlds[erow*330 + col] = f2b(acc[nt][r]);
        }
    }

    for (int e16 = 0; e16 < 16; ++e16){
        const int erow = w*16 + e16;
        float tw0 = b2f(twlds[erow*330 +   0 + lane]);
        float tw1 = b2f(twlds[erow*330 +  64 + lane]);
        float tw2 = b2f(twlds[erow*330 + 128 + lane]);
        float tw3 = b2f(twlds[erow*330 + 192 + lane]);
        float tw4 = b2f(twlds[erow*330 + 256 + lane]);
        const int snd = __shfl(sndreg, e16);
        const int rcv = __shfl(rcvreg, e16);
        float y0 = __shfl(yreg, e16*3+0);
        float y1 = __shfl(yreg, e16*3+1);
        float y2 = __shfl(yreg, e16*3+2);
        float ss  = b2f(s1[snd*64 + lane]);
        float vs0 = b2f(v1[(snd*3+0)*64 + lane]);
        float vs1 = b2f(v1[(snd*3+1)*64 + lane]);
        float vs2 = b2f(v1[(snd*3+2)*64 + lane]);
        float dot = vs0*y0 + vs1*y1 + vs2*y2;
        float c0 = vs1*y2 - vs2*y1;
        float c1 = vs2*y0 - vs0*y2;
        float c2 = vs0*y1 - vs1*y0;
        float ms  = tw0*ss + tw1*dot*kINV_SQRT3;
        float t2s = tw2*ss, t4 = tw4*kINV_SQRT2;
        float mv0 = t2s*y0 + tw3*vs0 + t4*c0;
        float mv1 = t2s*y1 + tw3*vs1 + t4*c1;
        float mv2 = t2s*y2 + tw3*vs2 + t4*c2;
        half2v p01 = { (_Float16)ms,  (_Float16)mv0 };
        half2v p23 = { (_Float16)mv1, (_Float16)mv2 };
        __builtin_amdgcn_global_atomic_fadd_v2f16(&Ah[rcv*128 + lane],      p01);
        __builtin_amdgcn_global_atomic_fadd_v2f16(&Ah[rcv*128 + 64 + lane], p23);
    }
}

// ---- Kernel C (MFMA, species-sorted tiles; vectorized gathers) --------------------------
__global__ __launch_bounds__(256) void knodeC2(
    const float* __restrict__ s, const float* __restrict__ v,
    const half2v* __restrict__ Ah,
    const unsigned short* __restrict__ P,
    const int* __restrict__ perm, const int* __restrict__ tspec,
    const float* __restrict__ wps, const float* __restrict__ wpv,
    const float* __restrict__ Wread,
    float* __restrict__ out)
{
    __shared__ unsigned short Bt[4][4][16*72];
    const int w = threadIdx.x >> 6, lane = threadIdx.x & 63;
    const int t = blockIdx.x*4 + w;
    if (t >= NTILES) return;
    const int mcol = lane & 15, quad = lane >> 4;
    const int spec = tspec[t];
    const int nA   = perm[t*16 + mcol];
    const short8* PB = (const short8*)P;
    const int sb = CWss + spec*512, vb = CWsv + spec*512;

    short8 fAs[2], fAv[3][2], fS[2], fV[3][2];
    if (nA >= 0){
        #pragma unroll
        for (int ks = 0; ks < 2; ++ks){
            const int k0 = ks*32 + quad*8;
            half2v pa[8], pb[8];
            *(float4v*)&pa[0] = *(const float4v*)&Ah[nA*128 + k0];
            *(float4v*)&pa[4] = *(const float4v*)&Ah[nA*128 + k0 + 4];
            *(float4v*)&pb[0] = *(const float4v*)&Ah[nA*128 + 64 + k0];
            *(float4v*)&pb[4] = *(const float4v*)&Ah[nA*128 + 64 + k0 + 4];
            float as_[8], a0_[8], a1_[8], a2_[8];
            #pragma unroll
            for (int j = 0; j < 8; ++j){
                as_[j] = (float)pa[j].x; a0_[j] = (float)pa[j].y;
                a1_[j] = (float)pb[j].x; a2_[j] = (float)pb[j].y;
            }
            fAs[ks] = pack8(as_); fAv[0][ks] = pack8(a0_);
            fAv[1][ks] = pack8(a1_); fAv[2][ks] = pack8(a2_);
            float ts[8];
            { float4v a = *(const float4v*)&s[nA*64 + k0];
              float4v b = *(const float4v*)&s[nA*64 + k0 + 4];
              #pragma unroll
              for (int j = 0; j < 4; ++j){ ts[j] = a[j]; ts[4+j] = b[j]; } }
            fS[ks] = pack8(ts);
            float tv[24];
            #pragma unroll
            for (int q = 0; q < 6; ++q){
                float4v x = *(const float4v*)&v[(nA*64 + k0)*3 + q*4];
                #pragma unroll
                for (int j = 0; j < 4; ++j) tv[q*4+j] = x[j];
            }
            #pragma unroll
            for (int c = 0; c < 3; ++c){
                float tc[8];
                #pragma unroll
                for (int j = 0; j < 8; ++j) tc[j] = tv[j*3 + c];
                fV[c][ks] = pack8(tc);
            }
        }
    } else {
        short8 z8 = {};
        #pragma unroll
        for (int ks = 0; ks < 2; ++ks){
            fAs[ks] = z8; fS[ks] = z8;
            #pragma unroll
            for (int c = 0; c < 3; ++c){ fAv[c][ks] = z8; fV[c][ks] = z8; }
        }
    }

    float4v z = {0.f,0.f,0.f,0.f};
    float4v scS[4], scV[3][4];
    #pragma unroll
    for (int nt = 0; nt < 4; ++nt){
        float4v Ais = __builtin_amdgcn_mfma_f32_16x16x32_bf16(fAs[0], PB[CWis+(nt*2+0)*64+lane], z, 0,0,0);
        Ais = __builtin_amdgcn_mfma_f32_16x16x32_bf16(fAs[1], PB[CWis+(nt*2+1)*64+lane], Ais, 0,0,0);
        float4v Aiv[3];
        #pragma unroll
        for (int c = 0; c < 3; ++c){
            Aiv[c] = __builtin_amdgcn_mfma_f32_16x16x32_bf16(fAv[c][0], PB[CWiv+(nt*2+0)*64+lane], z, 0,0,0);
            Aiv[c] = __builtin_amdgcn_mfma_f32_16x16x32_bf16(fAv[c][1], PB[CWiv+(nt*2+1)*64+lane], Aiv[c], 0,0,0);
        }
        scS[nt] = __builtin_amdgcn_mfma_f32_16x16x32_bf16(fS[0], PB[sb+(nt*2+0)*64+lane], z, 0,0,0);
        scS[nt] = __builtin_amdgcn_mfma_f32_16x16x32_bf16(fS[1], PB[sb+(nt*2+1)*64+lane], scS[nt], 0,0,0);
        #pragma unroll
        for (int c = 0; c < 3; ++c){
            scV[c][nt] = __builtin_amdgcn_mfma_f32_16x16x32_bf16(fV[c][0], PB[vb+(nt*2+0)*64+lane], z, 0,0,0);
            scV[c][nt] = __builtin_amdgcn_mfma_f32_16x16x32_bf16(fV[c][1], PB[vb+(nt*2+1)*64+lane], scV[c][nt], 0,0,0);
        }
        const int g = nt*16 + mcol;
        float w0 = wps[spec*320 +   0 + g], w1 = wps[spec*320 +  64 + g];
        float w2 = wps[spec*320 + 128 + g], w3 = wps[spec*320 + 192 + g];
        float w4 = wps[spec*320 + 256 + g];
        float u0 = wpv[spec*256 +   0 + g], u1 = wpv[spec*256 +  64 + g];
        float u2 = wpv[spec*256 + 128 + g], u3 = wpv[spec*256 + 192 + g];
        #pragma unroll
        for (int r = 0; r < 4; ++r){
            float A  = Ais[r]    * kINV_AVG;
            float a0 = Aiv[0][r] * kINV_AVG;
            float a1 = Aiv[1][r] * kINV_AVG;
            float a2 = Aiv[2][r] * kINV_AVG;
            float d   = a0*a0 + a1*a1 + a2*a2;
            float as2 = A*A;
            float Bs  = w0*A + w1*as2 + w2*d + w3*as2*A + w4*A*d;
            float gg  = u0 + u1*A + u2*as2 + u3*d;
            const int row = quad*4 + r;
            Bt[w][0][row*72 + g] = f2b(Bs);
            Bt[w][1][row*72 + g] = f2b(gg*a0);
            Bt[w][2][row*72 + g] = f2b(gg*a1);
            Bt[w][3][row*72 + g] = f2b(gg*a2);
        }
    }

    short8 bS[2], bV[3][2];
    #pragma unroll
    for (int ks = 0; ks < 2; ++ks){
        bS[ks] = *(const short8*)&Bt[w][0][mcol*72 + ks*32 + quad*8];
        #pragma unroll
        for (int c = 0; c < 3; ++c)
            bV[c][ks] = *(const short8*)&Bt[w][1+c][mcol*72 + ks*32 + quad*8];
    }

    float* out_node = out;
    float* out_s    = out + NNODES;
    float* out_v    = out + NNODES + NNODES*64;
    int ndr[4];
    #pragma unroll
    for (int r = 0; r < 4; ++r) ndr[r] = perm[t*16 + quad*4 + r];
    float4v rd = {0.f,0.f,0.f,0.f};
    #pragma unroll
    for (int nt = 0; nt < 4; ++nt){
        float4v oS = scS[nt];
        oS = __builtin_amdgcn_mfma_f32_16x16x32_bf16(bS[0], PB[CWps+(nt*2+0)*64+lane], oS, 0,0,0);
        oS = __builtin_amdgcn_mfma_f32_16x16x32_bf16(bS[1], PB[CWps+(nt*2+1)*64+lane], oS, 0,0,0);
        float4v oV[3];
        #pragma unroll
        for (int c = 0; c < 3; ++c){
            oV[c] = scV[c][nt];
            oV[c] = __builtin_amdgcn_mfma_f32_16x16x32_bf16(bV[c][0], PB[CWpv+(nt*2+0)*64+lane], oV[c], 0,0,0);
            oV[c] = __builtin_amdgcn_mfma_f32_16x16x32_bf16(bV[c][1], PB[CWpv+(nt*2+1)*64+lane], oV[c], 0,0,0);
        }
        const int g = nt*16 + mcol;
        float wr = Wread[g];
        #pragma unroll
        for (int r = 0; r < 4; ++r){
            if (ndr[r] >= 0){
                out_s[ndr[r]*64 + g] = oS[r];
                #pragma unroll
                for (int c = 0; c < 3; ++c) out_v[(ndr[r]*64 + g)*3 + c] = oV[c][r];
            }
            rd[r] += oS[r] * wr;
        }
    }
    #pragma unroll
    for (int off = 1; off < 16; off <<= 1){
        #pragma unroll
        for (int r = 0; r < 4; ++r) rd[r] += __shfl_xor(rd[r], off);
    }
    if (mcol == 0){
        #pragma unroll
        for (int r = 0; r < 4; ++r) if (ndr[r] >= 0) out_node[ndr[r]] = rd[r];
    }
}

extern "C" void kernel_launch(void* const* d_in, const int* in_sizes, int n_in,
                              void* d_out, int out_size, void* d_ws, size_t ws_size,
                              hipStream_t stream)
{
    (void)in_sizes; (void)n_in; (void)out_size; (void)ws_size;
    const float* s    = (const float*)d_in[0];
    const float* v    = (const float*)d_in[1];
    const float* Y1   = (const float*)d_in[2];
    const float* ef   = (const float*)d_in[3];
    const int* specie = (const int*)d_in[4];
    const int* senders   = (const int*)d_in[5];
    const int* receivers = (const int*)d_in[6];
    const float* Wls  = (const float*)d_in[7];
    const float* Wlv  = (const float*)d_in[8];
    const float* Wss  = (const float*)d_in[9];
    const float* Wsv  = (const float*)d_in[10];
    const float* Wr1  = (const float*)d_in[11];
    const float* Wr2  = (const float*)d_in[12];
    const float* Wis  = (const float*)d_in[13];
    const float* Wiv  = (const float*)d_in[14];
    const float* wps  = (const float*)d_in[15];
    const float* wpv  = (const float*)d_in[16];
    const float* Wps  = (const float*)d_in[17];
    const float* Wpv  = (const float*)d_in[18];
    const float* Wrd  = (const float*)d_in[19];

    float* out = (float*)d_out;
    unsigned short* t_s1 = (unsigned short*)(out + NNODES);   // bf16 temp in d_out
    unsigned short* t_v1 = t_s1 + NNODES*64;

    // ws layout:
    //  [0, 253952)            bf16 fragment pool P
    //  [262144, +10.24M)      Ah fp16 accumulator [N][2][64] half2
    //  [10502144, +80640)     perm[20160]
    //  [10582784, +5040)      tspec[1260]
    char* ws = (char*)d_ws;
    unsigned short* P = (unsigned short*)ws;
    half2v* Ah  = (half2v*)(ws + 262144);
    int* perm   = (int*)(ws + 10502144);
    int* tspec  = (int*)(ws + 10582784);

    kprep<<<63, 256, 0, stream>>>(specie, Wr2, Wls, Wlv, Wis, Wiv, Wps, Wpv, Wss, Wsv,
                                  P, perm, tspec);
    knodeA2<<<313, 256, 0, stream>>>(s, v, P, t_s1, t_v1, (float4v*)Ah);
    kedge2<<<5000, 256, 0, stream>>>(Y1, ef, senders, receivers, Wr1, P + CW2*8, t_s1, t_v1, Ah);
    knodeC2<<<315, 256, 0, stream>>>(s, v, Ah, P, perm, tspec, wps, wpv, Wrd, out);
}